// Round 8
// baseline (477.135 us; speedup 1.0000x reference)
//
#include <hip/hip_runtime.h>

typedef __attribute__((ext_vector_type(8))) short bf16x8;
typedef __attribute__((ext_vector_type(4))) float f32x4;
typedef __attribute__((ext_vector_type(2))) float f32x2;
typedef __attribute__((ext_vector_type(2))) unsigned u32x2;

#define N_NODES 50000
#define N_EDGES 800000
#define DIM 128
#define N_GRAPHS 128
#define N_CLASSES 10
#define BN_EPS 1e-5f
#define SCAN_NB ((N_NODES + 255) / 256)   // 196
#define FBLK ((N_NODES + 63) / 64)        // 782
#define NPART (FBLK * 4)                  // 3128 stat-partial rows

static __device__ __forceinline__ unsigned short f2bf(float f) {
    unsigned u = __float_as_uint(f);
    u += 0x7FFF + ((u >> 16) & 1);   // round-to-nearest-even
    return (unsigned short)(u >> 16);
}
static __device__ __forceinline__ float bf_lo(unsigned u) { return __uint_as_float(u << 16); }
static __device__ __forceinline__ float bf_hi(unsigned u) { return __uint_as_float(u & 0xffff0000u); }
static __device__ __forceinline__ unsigned packbf(float a, float b) {
    return (unsigned)f2bf(a) | ((unsigned)f2bf(b) << 16);
}

// ---- x (f32) -> xb (bf16 packed) ----
__global__ __launch_bounds__(256) void cvt_x(const f32x2* __restrict__ x,
                                             unsigned* __restrict__ xb, int n) {
    int t = blockIdx.x * 256 + threadIdx.x;
    if (t < n) { f32x2 v = x[t]; xb[t] = packbf(v[0], v[1]); }
}

// ---- CSR build: histogram of destinations ----
__global__ __launch_bounds__(256) void hist_dst(const int* __restrict__ ei, int* __restrict__ deg) {
    int e = blockIdx.x * 256 + threadIdx.x;
    if (e < N_EDGES) atomicAdd(&deg[ei[N_EDGES + e]], 1);
}

// ---- hierarchical scan ----
__global__ __launch_bounds__(256) void scan_reduce(const int* __restrict__ deg,
                                                   int* __restrict__ partials) {
    __shared__ int red[256];
    int idx = blockIdx.x * 256 + threadIdx.x;
    red[threadIdx.x] = (idx < N_NODES) ? deg[idx] : 0;
    __syncthreads();
#pragma unroll
    for (int off = 128; off >= 1; off >>= 1) {
        if (threadIdx.x < off) red[threadIdx.x] += red[threadIdx.x + off];
        __syncthreads();
    }
    if (threadIdx.x == 0) partials[blockIdx.x] = red[0];
}

__global__ __launch_bounds__(256) void scan_offsets(const int* __restrict__ partials,
                                                    int* __restrict__ offsets) {
    __shared__ int buf[256];
    int t = threadIdx.x;
    int v = (t < SCAN_NB) ? partials[t] : 0;
    buf[t] = v;
    __syncthreads();
#pragma unroll
    for (int off = 1; off < 256; off <<= 1) {
        int u = (t >= off) ? buf[t - off] : 0;
        __syncthreads();
        buf[t] += u;
        __syncthreads();
    }
    if (t < SCAN_NB) offsets[t] = buf[t] - v;
}

__global__ __launch_bounds__(256) void scan_apply(const int* __restrict__ deg,
                                                  const int* __restrict__ offsets,
                                                  int* __restrict__ row_start,
                                                  int* __restrict__ cursor) {
    __shared__ int buf[256];
    int t = threadIdx.x;
    int idx = blockIdx.x * 256 + t;
    int v = (idx < N_NODES) ? deg[idx] : 0;
    buf[t] = v;
    __syncthreads();
#pragma unroll
    for (int off = 1; off < 256; off <<= 1) {
        int u = (t >= off) ? buf[t - off] : 0;
        __syncthreads();
        buf[t] += u;
        __syncthreads();
    }
    int incl = buf[t] + offsets[blockIdx.x];
    int excl = incl - v;
    if (idx < N_NODES) {
        row_start[idx] = excl;
        cursor[idx] = excl;
        if (idx == N_NODES - 1) row_start[N_NODES] = incl;
    }
}

__global__ __launch_bounds__(256) void fill_csr(const int* __restrict__ ei,
                                                int* __restrict__ cursor,
                                                int* __restrict__ csr_src) {
    int e = blockIdx.x * 256 + threadIdx.x;
    if (e >= N_EDGES) return;
    int src = ei[e];
    int dst = ei[N_EDGES + e];
    int pos = atomicAdd(&cursor[dst], 1);
    csr_src[pos] = src;
}

// ---- graph segment starts via binary search (batch is sorted) ----
__global__ __launch_bounds__(256) void graph_starts(const int* __restrict__ batch,
                                                    int* __restrict__ gs) {
    int g = blockIdx.x * 256 + threadIdx.x;
    if (g > N_GRAPHS) return;
    int lo = 0, hi = N_NODES;
    while (lo < hi) {
        int mid = (lo + hi) >> 1;
        if (batch[mid] < g) lo = mid + 1; else hi = mid;
    }
    gs[g] = lo;
}

// ---- gather-sum aggregation on bf16 features; BN=true applies relu(f*sc+sh) ----
template <bool BN>
__global__ __launch_bounds__(256) void aggregate_bf(const unsigned* __restrict__ F,
                                                    unsigned* __restrict__ out,
                                                    const int* __restrict__ row_start,
                                                    const int* __restrict__ csr_src,
                                                    const float* __restrict__ scale,
                                                    const float* __restrict__ shift) {
    int wave = threadIdx.x >> 6, lane = threadIdx.x & 63;
    int v = blockIdx.x * 4 + wave;
    if (v >= N_NODES) return;
    float sc0 = 0.f, sc1 = 0.f, sh0 = 0.f, sh1 = 0.f;
    if (BN) {
        f32x2 s2 = ((const f32x2*)scale)[lane];
        f32x2 h2 = ((const f32x2*)shift)[lane];
        sc0 = s2[0]; sc1 = s2[1]; sh0 = h2[0]; sh1 = h2[1];
    }
    unsigned u = F[(size_t)v * 64 + lane];
    float a0 = bf_lo(u), a1 = bf_hi(u);
    if (BN) { a0 = fmaxf(a0 * sc0 + sh0, 0.f); a1 = fmaxf(a1 * sc1 + sh1, 0.f); }
    int e = row_start[v], end = row_start[v + 1];
    for (; e + 3 < end; e += 4) {
        unsigned ua = F[(size_t)csr_src[e] * 64 + lane];
        unsigned ub = F[(size_t)csr_src[e + 1] * 64 + lane];
        unsigned uc = F[(size_t)csr_src[e + 2] * 64 + lane];
        unsigned ud = F[(size_t)csr_src[e + 3] * 64 + lane];
        float p0 = bf_lo(ua), p1 = bf_hi(ua), q0 = bf_lo(ub), q1 = bf_hi(ub);
        float r0 = bf_lo(uc), r1 = bf_hi(uc), s0 = bf_lo(ud), s1 = bf_hi(ud);
        if (BN) {
            p0 = fmaxf(p0 * sc0 + sh0, 0.f); p1 = fmaxf(p1 * sc1 + sh1, 0.f);
            q0 = fmaxf(q0 * sc0 + sh0, 0.f); q1 = fmaxf(q1 * sc1 + sh1, 0.f);
            r0 = fmaxf(r0 * sc0 + sh0, 0.f); r1 = fmaxf(r1 * sc1 + sh1, 0.f);
            s0 = fmaxf(s0 * sc0 + sh0, 0.f); s1 = fmaxf(s1 * sc1 + sh1, 0.f);
        }
        a0 += (p0 + q0) + (r0 + s0);
        a1 += (p1 + q1) + (r1 + s1);
    }
    for (; e < end; ++e) {
        unsigned ua = F[(size_t)csr_src[e] * 64 + lane];
        float p0 = bf_lo(ua), p1 = bf_hi(ua);
        if (BN) { p0 = fmaxf(p0 * sc0 + sh0, 0.f); p1 = fmaxf(p1 * sc1 + sh1, 0.f); }
        a0 += p0; a1 += p1;
    }
    out[(size_t)v * 64 + lane] = packbf(a0, a1);
}

// ---- prep: permute W (f32 [128][128]) into bf16 B-fragment layout ----
__global__ __launch_bounds__(256) void prep_w(const float* __restrict__ W0,
                                              const float* __restrict__ W1,
                                              const float* __restrict__ W2,
                                              const float* __restrict__ W3,
                                              unsigned short* __restrict__ wf) {
    int t = blockIdx.x * 256 + threadIdx.x;
    if (t >= 4 * 16384) return;
    int m = t >> 14, rem = t & 16383;
    int e = rem & 7, lane = (rem >> 3) & 63, fi = rem >> 9;
    int ks = fi & 3, n = fi >> 2;
    int col = n * 16 + (lane & 15);
    int k = ks * 32 + ((lane >> 4) << 3) + e;
    const float* W = (m == 0) ? W0 : (m == 1) ? W1 : (m == 2) ? W2 : W3;
    wf[t] = f2bf(W[k * DIM + col]);
}

// ---- fused GIN layer: h = relu(A@Wa + ba) @ Wb + bb; per-wave stat partials ----
// LDS: one W buffer (32K, staged Wa then Wb) + mid (16K) = 48K -> 3 blocks/CU
__global__ __launch_bounds__(256, 3) void fused_layer(
        const unsigned short* __restrict__ A,   // [M][128] bf16
        const bf16x8* __restrict__ wfA_g,
        const bf16x8* __restrict__ wfB_g,
        const float* __restrict__ bias_a,
        const float* __restrict__ bias_b,
        unsigned short* __restrict__ out,       // [M][128] bf16
        float* __restrict__ psum,               // [NPART][128]
        float* __restrict__ psq, int M) {
    __shared__ bf16x8 wfS[2048];                // 32 KB, Wa then Wb
    __shared__ unsigned short mid[8192];        // 64 x 128

    int tid = threadIdx.x;
    int w = tid >> 6, lane = tid & 63;
    int cl = lane & 15, kq = lane >> 4;
    int rblk = blockIdx.x * 64;

    // issue Wb loads early; hold in regs while GEMM1 runs (async-stage split)
    bf16x8 wb[8];
#pragma unroll
    for (int i = 0; i < 8; ++i) wb[i] = wfB_g[i * 256 + tid];

    // stage Wa into LDS
#pragma unroll
    for (int i = 0; i < 8; ++i) wfS[i * 256 + tid] = wfA_g[i * 256 + tid];

    // A1 fragments: coalesced 16B/lane from row-major bf16
    int arow = rblk + w * 16 + cl;
    if (arow >= M) arow = M - 1;
    bf16x8 af[4];
    const unsigned short* Ap = A + (size_t)arow * DIM + kq * 8;
#pragma unroll
    for (int ks = 0; ks < 4; ++ks) af[ks] = *(const bf16x8*)(Ap + ks * 32);

    __syncthreads();   // Wa staged

    // GEMM1
    f32x4 acc[8];
#pragma unroll
    for (int n = 0; n < 8; ++n) acc[n] = f32x4{0.f, 0.f, 0.f, 0.f};
#pragma unroll
    for (int n = 0; n < 8; ++n)
#pragma unroll
        for (int ks = 0; ks < 4; ++ks)
            acc[n] = __builtin_amdgcn_mfma_f32_16x16x32_bf16(af[ks], wfS[(n * 4 + ks) * 64 + lane],
                                                             acc[n], 0, 0, 0);

    // epilogue 1: bias + relu -> mid (bf16, XOR-swizzled)
#pragma unroll
    for (int n = 0; n < 8; ++n) {
        int col = n * 16 + cl;
        float b = bias_a[col];
#pragma unroll
        for (int r = 0; r < 4; ++r) {
            int rl = w * 16 + kq * 4 + r;
            float v = fmaxf(acc[n][r] + b, 0.f);
            mid[(rl * DIM + col) ^ ((rl & 7) << 3)] = f2bf(v);
        }
    }
    __syncthreads();   // GEMM1 LDS reads done; mid written

    // stage Wb into the same LDS buffer (from regs)
#pragma unroll
    for (int i = 0; i < 8; ++i) wfS[i * 256 + tid] = wb[i];

    // A2 fragments from mid
    bf16x8 af2[4];
    {
        int rl = w * 16 + cl;
        int sw = (cl & 7) << 3;
#pragma unroll
        for (int ks = 0; ks < 4; ++ks)
            af2[ks] = *(const bf16x8*)(mid + ((rl * DIM + kq * 8 + ks * 32) ^ sw));
    }
    __syncthreads();   // Wb staged

    // GEMM2
    f32x4 acc2[8];
#pragma unroll
    for (int n = 0; n < 8; ++n) acc2[n] = f32x4{0.f, 0.f, 0.f, 0.f};
#pragma unroll
    for (int n = 0; n < 8; ++n)
#pragma unroll
        for (int ks = 0; ks < 4; ++ks)
            acc2[n] = __builtin_amdgcn_mfma_f32_16x16x32_bf16(af2[ks], wfS[(n * 4 + ks) * 64 + lane],
                                                              acc2[n], 0, 0, 0);

    // epilogue 2: bias + per-wave stat partials (NO atomics); park bf16 in mid
    int prow = blockIdx.x * 4 + w;
#pragma unroll
    for (int n = 0; n < 8; ++n) {
        int col = n * 16 + cl;
        float b = bias_b[col];
        float s = 0.f, q = 0.f;
#pragma unroll
        for (int r = 0; r < 4; ++r) {
            int rl = w * 16 + kq * 4 + r;
            float v = acc2[n][r] + b;
            if (rblk + rl < M) { s += v; q += v * v; }
            mid[(rl * DIM + col) ^ ((rl & 7) << 3)] = f2bf(v);
        }
        s += __shfl_xor(s, 16, 64);
        s += __shfl_xor(s, 32, 64);
        q += __shfl_xor(q, 16, 64);
        q += __shfl_xor(q, 32, 64);
        if (kq == 0) {
            psum[(size_t)prow * DIM + col] = s;
            psq[(size_t)prow * DIM + col] = q;
        }
    }

    // bounce-store: coalesced 16B/lane stores (wave-private mid slice, no barrier)
    {
        int r4 = lane >> 4, c = lane & 15;
#pragma unroll
        for (int rb = 0; rb < 4; ++rb) {
            int rl = w * 16 + rb * 4 + r4;
            int grow = rblk + rl;
            bf16x8 v = *(const bf16x8*)(mid + ((rl * DIM + c * 8) ^ ((rl & 7) << 3)));
            if (grow < M) *(bf16x8*)(out + (size_t)grow * DIM + c * 8) = v;
        }
    }
}

// ---- BN finalize: reduce stat partials, compute scale/shift ----
__global__ __launch_bounds__(256) void bn_finalize(const float* __restrict__ psum,
                                                   const float* __restrict__ psq,
                                                   const float* __restrict__ g,
                                                   const float* __restrict__ be,
                                                   float* __restrict__ scale,
                                                   float* __restrict__ shift) {
    __shared__ float sums[128], sqs[128];
    int t = threadIdx.x;
    int c = t & 127;
    const float* src = (t < 128) ? psum : psq;
    float acc = 0.f;
    for (int r = 0; r < NPART; r += 4) {
        acc += src[(size_t)(r + 0) * DIM + c] + src[(size_t)(r + 1) * DIM + c] +
               src[(size_t)(r + 2) * DIM + c] + src[(size_t)(r + 3) * DIM + c];
    }
    if (t < 128) sums[c] = acc; else sqs[c] = acc;
    __syncthreads();
    if (t < 128) {
        const float invN = 1.0f / (float)N_NODES;
        float mu = sums[c] * invN;
        float var = sqs[c] * invN - mu * mu;
        float rs = rsqrtf(var + BN_EPS) * g[c];
        scale[c] = rs;
        shift[c] = be[c] - mu * rs;
    }
}

// ---- BN apply + ReLU + segmented pool (bf16 input): one block per graph ----
__global__ __launch_bounds__(256) void bn_pool(const unsigned short* __restrict__ h,
                                               const float* __restrict__ scale,
                                               const float* __restrict__ shift,
                                               const int* __restrict__ gs,
                                               float* __restrict__ pooled) {
    int g = blockIdx.x;
    int t = threadIdx.x;
    int c4 = t & 31;
    int rs = t >> 5;
    int r0 = gs[g], r1 = gs[g + 1];
    f32x4 sc = ((const f32x4*)scale)[c4];
    f32x4 sh = ((const f32x4*)shift)[c4];
    f32x4 acc = f32x4{0.f, 0.f, 0.f, 0.f};
    for (int r = r0 + rs; r < r1; r += 8) {
        u32x2 u = *(const u32x2*)(h + (size_t)r * DIM + c4 * 4);
        float f0 = bf_lo(u[0]), f1 = bf_hi(u[0]), f2 = bf_lo(u[1]), f3 = bf_hi(u[1]);
        acc[0] += fmaxf(f0 * sc[0] + sh[0], 0.f);
        acc[1] += fmaxf(f1 * sc[1] + sh[1], 0.f);
        acc[2] += fmaxf(f2 * sc[2] + sh[2], 0.f);
        acc[3] += fmaxf(f3 * sc[3] + sh[3], 0.f);
    }
    __shared__ f32x4 red[256];
    red[t] = acc;
    __syncthreads();
#pragma unroll
    for (int off = 128; off >= 32; off >>= 1) {
        if (t < off) red[t] += red[t + off];
        __syncthreads();
    }
    if (t < 32) ((f32x4*)pooled)[g * 32 + c4] = red[t];
}

// ---- final: out[g][c] = pooled[g] . Wo[:,c] + bo[c] ----
__global__ __launch_bounds__(256) void final_gemm(const float* __restrict__ pooled,
                                                  const float* __restrict__ Wo,
                                                  const float* __restrict__ bo,
                                                  float* __restrict__ out) {
    int t = blockIdx.x * 256 + threadIdx.x;
    if (t >= N_GRAPHS * N_CLASSES) return;
    int g = t / N_CLASSES, c = t - g * N_CLASSES;
    float s = bo[c];
    const float* p = pooled + (size_t)g * DIM;
#pragma unroll 4
    for (int k = 0; k < DIM; ++k) s += p[k] * Wo[k * N_CLASSES + c];
    out[t] = s;
}

extern "C" void kernel_launch(void* const* d_in, const int* in_sizes, int n_in,
                              void* d_out, int out_size, void* d_ws, size_t ws_size,
                              hipStream_t stream) {
    const float* x   = (const float*)d_in[0];
    const int* ei    = (const int*)d_in[1];   // harness: integer -> int32
    const int* batch = (const int*)d_in[2];
    const float* W1a = (const float*)d_in[3];
    const float* b1a = (const float*)d_in[4];
    const float* W1b = (const float*)d_in[5];
    const float* b1b = (const float*)d_in[6];
    const float* g1  = (const float*)d_in[7];
    const float* be1 = (const float*)d_in[8];
    const float* W2a = (const float*)d_in[9];
    const float* b2a = (const float*)d_in[10];
    const float* W2b = (const float*)d_in[11];
    const float* b2b = (const float*)d_in[12];
    const float* g2  = (const float*)d_in[13];
    const float* be2 = (const float*)d_in[14];
    const float* Wo  = (const float*)d_in[15];
    const float* bo  = (const float*)d_in[16];

    char* ws = (char*)d_ws;
    const size_t NBH = (size_t)N_NODES * DIM * 2;   // 12.8 MB (bf16 node features)
    unsigned short* xb   = (unsigned short*)ws;
    unsigned short* aggb = (unsigned short*)(ws + NBH);
    unsigned short* hb   = (unsigned short*)(ws + 2 * NBH);
    unsigned short* wfrag = (unsigned short*)(ws + 3 * NBH);   // 128 KB
    float* psum = (float*)(ws + 3 * NBH + 4 * 16384 * 2);      // NPART*128
    float* psq  = psum + (size_t)NPART * DIM;
    char* smallb = (char*)(psq + (size_t)NPART * DIM);
    float* pooled  = (float*)smallb;               // 128*128
    float* scale1  = pooled + N_GRAPHS * DIM;
    float* shift1  = scale1 + 128;
    float* scale2  = scale1 + 256;
    float* shift2  = scale1 + 384;
    int* gs        = (int*)(shift2 + 128);     // N_GRAPHS+1
    int* deg       = gs + N_GRAPHS + 1;
    int* row_start = deg + N_NODES;            // N_NODES+1
    int* cursor    = row_start + N_NODES + 1;
    int* partials  = cursor + N_NODES;         // SCAN_NB
    int* offsets   = partials + SCAN_NB;       // SCAN_NB
    int* csr_src   = offsets + SCAN_NB;        // N_EDGES

    hipMemsetAsync(deg, 0, N_NODES * 4, stream);

    const int nv2 = N_NODES * 64;  // f32x2 count
    cvt_x<<<(nv2 + 255) / 256, 256, 0, stream>>>((const f32x2*)x, (unsigned*)xb, nv2);
    prep_w<<<256, 256, 0, stream>>>(W1a, W1b, W2a, W2b, wfrag);
    graph_starts<<<1, 256, 0, stream>>>(batch, gs);

    const int eblk = (N_EDGES + 255) / 256;
    hist_dst<<<eblk, 256, 0, stream>>>(ei, deg);
    scan_reduce<<<SCAN_NB, 256, 0, stream>>>(deg, partials);
    scan_offsets<<<1, 256, 0, stream>>>(partials, offsets);
    scan_apply<<<SCAN_NB, 256, 0, stream>>>(deg, offsets, row_start, cursor);
    fill_csr<<<eblk, 256, 0, stream>>>(ei, cursor, csr_src);

    const int ablk = (N_NODES + 3) / 4;

    // layer 1
    aggregate_bf<false><<<ablk, 256, 0, stream>>>((const unsigned*)xb, (unsigned*)aggb,
                                                  row_start, csr_src, nullptr, nullptr);
    fused_layer<<<FBLK, 256, 0, stream>>>(
        aggb, (const bf16x8*)(wfrag + 0 * 16384), (const bf16x8*)(wfrag + 1 * 16384),
        b1a, b1b, hb, psum, psq, N_NODES);
    bn_finalize<<<1, 256, 0, stream>>>(psum, psq, g1, be1, scale1, shift1);

    // layer 2 (BN1+ReLU fused into aggregate)
    aggregate_bf<true><<<ablk, 256, 0, stream>>>((const unsigned*)hb, (unsigned*)aggb,
                                                 row_start, csr_src, scale1, shift1);
    fused_layer<<<FBLK, 256, 0, stream>>>(
        aggb, (const bf16x8*)(wfrag + 2 * 16384), (const bf16x8*)(wfrag + 3 * 16384),
        b2a, b2b, hb, psum, psq, N_NODES);
    bn_finalize<<<1, 256, 0, stream>>>(psum, psq, g2, be2, scale2, shift2);
    bn_pool<<<N_GRAPHS, 256, 0, stream>>>(hb, scale2, shift2, gs, pooled);

    final_gemm<<<(N_GRAPHS * N_CLASSES + 255) / 256, 256, 0, stream>>>(pooled, Wo, bo,
                                                                       (float*)d_out);
}

// Round 9
// 306.163 us; speedup vs baseline: 1.5584x; 1.5584x over previous
//
#include <hip/hip_runtime.h>

typedef __attribute__((ext_vector_type(8))) short bf16x8;
typedef __attribute__((ext_vector_type(4))) float f32x4;
typedef __attribute__((ext_vector_type(2))) float f32x2;
typedef __attribute__((ext_vector_type(2))) unsigned u32x2;

#define N_NODES 50000
#define N_EDGES 800000
#define DIM 128
#define N_GRAPHS 128
#define N_CLASSES 10
#define BN_EPS 1e-5f
#define SCAN_NB ((N_NODES + 255) / 256)   // 196
#define FBLK ((N_NODES + 63) / 64)        // 782
#define NPART (FBLK * 4)                  // 3128 stat-partial rows
#define RED_NB 64                         // stage-1 reduction blocks
#define RED_ROWS ((NPART + RED_NB - 1) / RED_NB)   // 49

static __device__ __forceinline__ unsigned short f2bf(float f) {
    unsigned u = __float_as_uint(f);
    u += 0x7FFF + ((u >> 16) & 1);   // round-to-nearest-even
    return (unsigned short)(u >> 16);
}
static __device__ __forceinline__ float bf_lo(unsigned u) { return __uint_as_float(u << 16); }
static __device__ __forceinline__ float bf_hi(unsigned u) { return __uint_as_float(u & 0xffff0000u); }
static __device__ __forceinline__ unsigned packbf(float a, float b) {
    return (unsigned)f2bf(a) | ((unsigned)f2bf(b) << 16);
}

// ---- x (f32) -> xb (bf16 packed) ----
__global__ __launch_bounds__(256) void cvt_x(const f32x2* __restrict__ x,
                                             unsigned* __restrict__ xb, int n) {
    int t = blockIdx.x * 256 + threadIdx.x;
    if (t < n) { f32x2 v = x[t]; xb[t] = packbf(v[0], v[1]); }
}

// ---- CSR build: histogram of destinations ----
__global__ __launch_bounds__(256) void hist_dst(const int* __restrict__ ei, int* __restrict__ deg) {
    int e = blockIdx.x * 256 + threadIdx.x;
    if (e < N_EDGES) atomicAdd(&deg[ei[N_EDGES + e]], 1);
}

// ---- hierarchical scan ----
__global__ __launch_bounds__(256) void scan_reduce(const int* __restrict__ deg,
                                                   int* __restrict__ partials) {
    __shared__ int red[256];
    int idx = blockIdx.x * 256 + threadIdx.x;
    red[threadIdx.x] = (idx < N_NODES) ? deg[idx] : 0;
    __syncthreads();
#pragma unroll
    for (int off = 128; off >= 1; off >>= 1) {
        if (threadIdx.x < off) red[threadIdx.x] += red[threadIdx.x + off];
        __syncthreads();
    }
    if (threadIdx.x == 0) partials[blockIdx.x] = red[0];
}

__global__ __launch_bounds__(256) void scan_offsets(const int* __restrict__ partials,
                                                    int* __restrict__ offsets) {
    __shared__ int buf[256];
    int t = threadIdx.x;
    int v = (t < SCAN_NB) ? partials[t] : 0;
    buf[t] = v;
    __syncthreads();
#pragma unroll
    for (int off = 1; off < 256; off <<= 1) {
        int u = (t >= off) ? buf[t - off] : 0;
        __syncthreads();
        buf[t] += u;
        __syncthreads();
    }
    if (t < SCAN_NB) offsets[t] = buf[t] - v;
}

__global__ __launch_bounds__(256) void scan_apply(const int* __restrict__ deg,
                                                  const int* __restrict__ offsets,
                                                  int* __restrict__ row_start,
                                                  int* __restrict__ cursor) {
    __shared__ int buf[256];
    int t = threadIdx.x;
    int idx = blockIdx.x * 256 + t;
    int v = (idx < N_NODES) ? deg[idx] : 0;
    buf[t] = v;
    __syncthreads();
#pragma unroll
    for (int off = 1; off < 256; off <<= 1) {
        int u = (t >= off) ? buf[t - off] : 0;
        __syncthreads();
        buf[t] += u;
        __syncthreads();
    }
    int incl = buf[t] + offsets[blockIdx.x];
    int excl = incl - v;
    if (idx < N_NODES) {
        row_start[idx] = excl;
        cursor[idx] = excl;
        if (idx == N_NODES - 1) row_start[N_NODES] = incl;
    }
}

__global__ __launch_bounds__(256) void fill_csr(const int* __restrict__ ei,
                                                int* __restrict__ cursor,
                                                int* __restrict__ csr_src) {
    int e = blockIdx.x * 256 + threadIdx.x;
    if (e >= N_EDGES) return;
    int src = ei[e];
    int dst = ei[N_EDGES + e];
    int pos = atomicAdd(&cursor[dst], 1);
    csr_src[pos] = src;
}

// ---- graph segment starts via binary search (batch is sorted) ----
__global__ __launch_bounds__(256) void graph_starts(const int* __restrict__ batch,
                                                    int* __restrict__ gs) {
    int g = blockIdx.x * 256 + threadIdx.x;
    if (g > N_GRAPHS) return;
    int lo = 0, hi = N_NODES;
    while (lo < hi) {
        int mid = (lo + hi) >> 1;
        if (batch[mid] < g) lo = mid + 1; else hi = mid;
    }
    gs[g] = lo;
}

// ---- gather-sum aggregation on bf16 features; BN=true applies relu(f*sc+sh) ----
template <bool BN>
__global__ __launch_bounds__(256) void aggregate_bf(const unsigned* __restrict__ F,
                                                    unsigned* __restrict__ out,
                                                    const int* __restrict__ row_start,
                                                    const int* __restrict__ csr_src,
                                                    const float* __restrict__ scale,
                                                    const float* __restrict__ shift) {
    int wave = threadIdx.x >> 6, lane = threadIdx.x & 63;
    int v = blockIdx.x * 4 + wave;
    if (v >= N_NODES) return;
    float sc0 = 0.f, sc1 = 0.f, sh0 = 0.f, sh1 = 0.f;
    if (BN) {
        f32x2 s2 = ((const f32x2*)scale)[lane];
        f32x2 h2 = ((const f32x2*)shift)[lane];
        sc0 = s2[0]; sc1 = s2[1]; sh0 = h2[0]; sh1 = h2[1];
    }
    unsigned u = F[(size_t)v * 64 + lane];
    float a0 = bf_lo(u), a1 = bf_hi(u);
    if (BN) { a0 = fmaxf(a0 * sc0 + sh0, 0.f); a1 = fmaxf(a1 * sc1 + sh1, 0.f); }
    int e = row_start[v], end = row_start[v + 1];
    for (; e + 3 < end; e += 4) {
        unsigned ua = F[(size_t)csr_src[e] * 64 + lane];
        unsigned ub = F[(size_t)csr_src[e + 1] * 64 + lane];
        unsigned uc = F[(size_t)csr_src[e + 2] * 64 + lane];
        unsigned ud = F[(size_t)csr_src[e + 3] * 64 + lane];
        float p0 = bf_lo(ua), p1 = bf_hi(ua), q0 = bf_lo(ub), q1 = bf_hi(ub);
        float r0 = bf_lo(uc), r1 = bf_hi(uc), s0 = bf_lo(ud), s1 = bf_hi(ud);
        if (BN) {
            p0 = fmaxf(p0 * sc0 + sh0, 0.f); p1 = fmaxf(p1 * sc1 + sh1, 0.f);
            q0 = fmaxf(q0 * sc0 + sh0, 0.f); q1 = fmaxf(q1 * sc1 + sh1, 0.f);
            r0 = fmaxf(r0 * sc0 + sh0, 0.f); r1 = fmaxf(r1 * sc1 + sh1, 0.f);
            s0 = fmaxf(s0 * sc0 + sh0, 0.f); s1 = fmaxf(s1 * sc1 + sh1, 0.f);
        }
        a0 += (p0 + q0) + (r0 + s0);
        a1 += (p1 + q1) + (r1 + s1);
    }
    for (; e < end; ++e) {
        unsigned ua = F[(size_t)csr_src[e] * 64 + lane];
        float p0 = bf_lo(ua), p1 = bf_hi(ua);
        if (BN) { p0 = fmaxf(p0 * sc0 + sh0, 0.f); p1 = fmaxf(p1 * sc1 + sh1, 0.f); }
        a0 += p0; a1 += p1;
    }
    out[(size_t)v * 64 + lane] = packbf(a0, a1);
}

// ---- prep: permute W (f32 [128][128]) into bf16 B-fragment layout ----
__global__ __launch_bounds__(256) void prep_w(const float* __restrict__ W0,
                                              const float* __restrict__ W1,
                                              const float* __restrict__ W2,
                                              const float* __restrict__ W3,
                                              unsigned short* __restrict__ wf) {
    int t = blockIdx.x * 256 + threadIdx.x;
    if (t >= 4 * 16384) return;
    int m = t >> 14, rem = t & 16383;
    int e = rem & 7, lane = (rem >> 3) & 63, fi = rem >> 9;
    int ks = fi & 3, n = fi >> 2;
    int col = n * 16 + (lane & 15);
    int k = ks * 32 + ((lane >> 4) << 3) + e;
    const float* W = (m == 0) ? W0 : (m == 1) ? W1 : (m == 2) ? W2 : W3;
    wf[t] = f2bf(W[k * DIM + col]);
}

// ---- fused GIN layer: h = relu(A@Wa + ba) @ Wb + bb; per-wave stat partials ----
// LDS: one W buffer (32K, staged Wa then Wb) + mid (16K) = 48K -> 3 blocks/CU
__global__ __launch_bounds__(256, 3) void fused_layer(
        const unsigned short* __restrict__ A,   // [M][128] bf16
        const bf16x8* __restrict__ wfA_g,
        const bf16x8* __restrict__ wfB_g,
        const float* __restrict__ bias_a,
        const float* __restrict__ bias_b,
        unsigned short* __restrict__ out,       // [M][128] bf16
        float* __restrict__ psum,               // [NPART][128]
        float* __restrict__ psq, int M) {
    __shared__ bf16x8 wfS[2048];                // 32 KB, Wa then Wb
    __shared__ unsigned short mid[8192];        // 64 x 128

    int tid = threadIdx.x;
    int w = tid >> 6, lane = tid & 63;
    int cl = lane & 15, kq = lane >> 4;
    int rblk = blockIdx.x * 64;

    // issue Wb loads early; hold in regs while GEMM1 runs (async-stage split)
    bf16x8 wb[8];
#pragma unroll
    for (int i = 0; i < 8; ++i) wb[i] = wfB_g[i * 256 + tid];

    // stage Wa into LDS
#pragma unroll
    for (int i = 0; i < 8; ++i) wfS[i * 256 + tid] = wfA_g[i * 256 + tid];

    // A1 fragments: coalesced 16B/lane from row-major bf16
    int arow = rblk + w * 16 + cl;
    if (arow >= M) arow = M - 1;
    bf16x8 af[4];
    const unsigned short* Ap = A + (size_t)arow * DIM + kq * 8;
#pragma unroll
    for (int ks = 0; ks < 4; ++ks) af[ks] = *(const bf16x8*)(Ap + ks * 32);

    __syncthreads();   // Wa staged

    // GEMM1
    f32x4 acc[8];
#pragma unroll
    for (int n = 0; n < 8; ++n) acc[n] = f32x4{0.f, 0.f, 0.f, 0.f};
#pragma unroll
    for (int n = 0; n < 8; ++n)
#pragma unroll
        for (int ks = 0; ks < 4; ++ks)
            acc[n] = __builtin_amdgcn_mfma_f32_16x16x32_bf16(af[ks], wfS[(n * 4 + ks) * 64 + lane],
                                                             acc[n], 0, 0, 0);

    // epilogue 1: bias + relu -> mid (bf16, XOR-swizzled)
#pragma unroll
    for (int n = 0; n < 8; ++n) {
        int col = n * 16 + cl;
        float b = bias_a[col];
#pragma unroll
        for (int r = 0; r < 4; ++r) {
            int rl = w * 16 + kq * 4 + r;
            float v = fmaxf(acc[n][r] + b, 0.f);
            mid[(rl * DIM + col) ^ ((rl & 7) << 3)] = f2bf(v);
        }
    }
    __syncthreads();   // GEMM1 LDS reads done; mid written

    // stage Wb into the same LDS buffer (from regs)
#pragma unroll
    for (int i = 0; i < 8; ++i) wfS[i * 256 + tid] = wb[i];

    // A2 fragments from mid
    bf16x8 af2[4];
    {
        int rl = w * 16 + cl;
        int sw = (cl & 7) << 3;
#pragma unroll
        for (int ks = 0; ks < 4; ++ks)
            af2[ks] = *(const bf16x8*)(mid + ((rl * DIM + kq * 8 + ks * 32) ^ sw));
    }
    __syncthreads();   // Wb staged

    // GEMM2
    f32x4 acc2[8];
#pragma unroll
    for (int n = 0; n < 8; ++n) acc2[n] = f32x4{0.f, 0.f, 0.f, 0.f};
#pragma unroll
    for (int n = 0; n < 8; ++n)
#pragma unroll
        for (int ks = 0; ks < 4; ++ks)
            acc2[n] = __builtin_amdgcn_mfma_f32_16x16x32_bf16(af2[ks], wfS[(n * 4 + ks) * 64 + lane],
                                                              acc2[n], 0, 0, 0);

    // epilogue 2: bias + per-wave stat partials (NO atomics); park bf16 in mid
    int prow = blockIdx.x * 4 + w;
#pragma unroll
    for (int n = 0; n < 8; ++n) {
        int col = n * 16 + cl;
        float b = bias_b[col];
        float s = 0.f, q = 0.f;
#pragma unroll
        for (int r = 0; r < 4; ++r) {
            int rl = w * 16 + kq * 4 + r;
            float v = acc2[n][r] + b;
            if (rblk + rl < M) { s += v; q += v * v; }
            mid[(rl * DIM + col) ^ ((rl & 7) << 3)] = f2bf(v);
        }
        s += __shfl_xor(s, 16, 64);
        s += __shfl_xor(s, 32, 64);
        q += __shfl_xor(q, 16, 64);
        q += __shfl_xor(q, 32, 64);
        if (kq == 0) {
            psum[(size_t)prow * DIM + col] = s;
            psq[(size_t)prow * DIM + col] = q;
        }
    }

    // bounce-store: coalesced 16B/lane stores (wave-private mid slice, no barrier)
    {
        int r4 = lane >> 4, c = lane & 15;
#pragma unroll
        for (int rb = 0; rb < 4; ++rb) {
            int rl = w * 16 + rb * 4 + r4;
            int grow = rblk + rl;
            bf16x8 v = *(const bf16x8*)(mid + ((rl * DIM + c * 8) ^ ((rl & 7) << 3)));
            if (grow < M) *(bf16x8*)(out + (size_t)grow * DIM + c * 8) = v;
        }
    }
}

// ---- stats reduction stage 1: 64 blocks, coalesced ----
__global__ __launch_bounds__(256) void reduce_stats(const float* __restrict__ psum,
                                                    const float* __restrict__ psq,
                                                    float* __restrict__ ps2) {
    int b = blockIdx.x, t = threadIdx.x;
    int c = t & 127;
    const float* src = (t < 128) ? psum : psq;
    int r0 = b * RED_ROWS;
    int r1 = min(NPART, r0 + RED_ROWS);
    float acc = 0.f;
    for (int r = r0; r < r1; ++r) acc += src[(size_t)r * DIM + c];
    ps2[(size_t)b * 256 + t] = acc;
}

// ---- BN finalize: reduce 64 stage-1 partials, compute scale/shift ----
__global__ __launch_bounds__(256) void bn_finalize(const float* __restrict__ ps2,
                                                   const float* __restrict__ g,
                                                   const float* __restrict__ be,
                                                   float* __restrict__ scale,
                                                   float* __restrict__ shift) {
    __shared__ float sums[128], sqs[128];
    int t = threadIdx.x;
    int c = t & 127;
    float acc = 0.f;
#pragma unroll 4
    for (int r = 0; r < RED_NB; ++r) acc += ps2[(size_t)r * 256 + t];
    if (t < 128) sums[c] = acc; else sqs[c] = acc;
    __syncthreads();
    if (t < 128) {
        const float invN = 1.0f / (float)N_NODES;
        float mu = sums[c] * invN;
        float var = sqs[c] * invN - mu * mu;
        float rs = rsqrtf(var + BN_EPS) * g[c];
        scale[c] = rs;
        shift[c] = be[c] - mu * rs;
    }
}

// ---- BN apply + ReLU + segmented pool (bf16 input): one block per graph ----
__global__ __launch_bounds__(256) void bn_pool(const unsigned short* __restrict__ h,
                                               const float* __restrict__ scale,
                                               const float* __restrict__ shift,
                                               const int* __restrict__ gs,
                                               float* __restrict__ pooled) {
    int g = blockIdx.x;
    int t = threadIdx.x;
    int c4 = t & 31;
    int rs = t >> 5;
    int r0 = gs[g], r1 = gs[g + 1];
    f32x4 sc = ((const f32x4*)scale)[c4];
    f32x4 sh = ((const f32x4*)shift)[c4];
    f32x4 acc = f32x4{0.f, 0.f, 0.f, 0.f};
    for (int r = r0 + rs; r < r1; r += 8) {
        u32x2 u = *(const u32x2*)(h + (size_t)r * DIM + c4 * 4);
        float f0 = bf_lo(u[0]), f1 = bf_hi(u[0]), f2 = bf_lo(u[1]), f3 = bf_hi(u[1]);
        acc[0] += fmaxf(f0 * sc[0] + sh[0], 0.f);
        acc[1] += fmaxf(f1 * sc[1] + sh[1], 0.f);
        acc[2] += fmaxf(f2 * sc[2] + sh[2], 0.f);
        acc[3] += fmaxf(f3 * sc[3] + sh[3], 0.f);
    }
    __shared__ f32x4 red[256];
    red[t] = acc;
    __syncthreads();
#pragma unroll
    for (int off = 128; off >= 32; off >>= 1) {
        if (t < off) red[t] += red[t + off];
        __syncthreads();
    }
    if (t < 32) ((f32x4*)pooled)[g * 32 + c4] = red[t];
}

// ---- final: out[g][c] = pooled[g] . Wo[:,c] + bo[c] ----
__global__ __launch_bounds__(256) void final_gemm(const float* __restrict__ pooled,
                                                  const float* __restrict__ Wo,
                                                  const float* __restrict__ bo,
                                                  float* __restrict__ out) {
    int t = blockIdx.x * 256 + threadIdx.x;
    if (t >= N_GRAPHS * N_CLASSES) return;
    int g = t / N_CLASSES, c = t - g * N_CLASSES;
    float s = bo[c];
    const float* p = pooled + (size_t)g * DIM;
#pragma unroll 4
    for (int k = 0; k < DIM; ++k) s += p[k] * Wo[k * N_CLASSES + c];
    out[t] = s;
}

extern "C" void kernel_launch(void* const* d_in, const int* in_sizes, int n_in,
                              void* d_out, int out_size, void* d_ws, size_t ws_size,
                              hipStream_t stream) {
    const float* x   = (const float*)d_in[0];
    const int* ei    = (const int*)d_in[1];   // harness: integer -> int32
    const int* batch = (const int*)d_in[2];
    const float* W1a = (const float*)d_in[3];
    const float* b1a = (const float*)d_in[4];
    const float* W1b = (const float*)d_in[5];
    const float* b1b = (const float*)d_in[6];
    const float* g1  = (const float*)d_in[7];
    const float* be1 = (const float*)d_in[8];
    const float* W2a = (const float*)d_in[9];
    const float* b2a = (const float*)d_in[10];
    const float* W2b = (const float*)d_in[11];
    const float* b2b = (const float*)d_in[12];
    const float* g2  = (const float*)d_in[13];
    const float* be2 = (const float*)d_in[14];
    const float* Wo  = (const float*)d_in[15];
    const float* bo  = (const float*)d_in[16];

    char* ws = (char*)d_ws;
    const size_t NBH = (size_t)N_NODES * DIM * 2;   // 12.8 MB (bf16 node features)
    unsigned short* xb   = (unsigned short*)ws;
    unsigned short* aggb = (unsigned short*)(ws + NBH);
    unsigned short* hb   = (unsigned short*)(ws + 2 * NBH);
    unsigned short* wfrag = (unsigned short*)(ws + 3 * NBH);   // 128 KB
    float* psum = (float*)(ws + 3 * NBH + 4 * 16384 * 2);      // NPART*128
    float* psq  = psum + (size_t)NPART * DIM;
    float* ps2  = psq + (size_t)NPART * DIM;       // RED_NB*256
    char* smallb = (char*)(ps2 + RED_NB * 256);
    float* pooled  = (float*)smallb;               // 128*128
    float* scale1  = pooled + N_GRAPHS * DIM;
    float* shift1  = scale1 + 128;
    float* scale2  = scale1 + 256;
    float* shift2  = scale1 + 384;
    int* gs        = (int*)(shift2 + 128);     // N_GRAPHS+1
    int* deg       = gs + N_GRAPHS + 1;
    int* row_start = deg + N_NODES;            // N_NODES+1
    int* cursor    = row_start + N_NODES + 1;
    int* partials  = cursor + N_NODES;         // SCAN_NB
    int* offsets   = partials + SCAN_NB;       // SCAN_NB
    int* csr_src   = offsets + SCAN_NB;        // N_EDGES

    hipMemsetAsync(deg, 0, N_NODES * 4, stream);

    const int nv2 = N_NODES * 64;  // f32x2 count
    cvt_x<<<(nv2 + 255) / 256, 256, 0, stream>>>((const f32x2*)x, (unsigned*)xb, nv2);
    prep_w<<<256, 256, 0, stream>>>(W1a, W1b, W2a, W2b, wfrag);
    graph_starts<<<1, 256, 0, stream>>>(batch, gs);

    const int eblk = (N_EDGES + 255) / 256;
    hist_dst<<<eblk, 256, 0, stream>>>(ei, deg);
    scan_reduce<<<SCAN_NB, 256, 0, stream>>>(deg, partials);
    scan_offsets<<<1, 256, 0, stream>>>(partials, offsets);
    scan_apply<<<SCAN_NB, 256, 0, stream>>>(deg, offsets, row_start, cursor);
    fill_csr<<<eblk, 256, 0, stream>>>(ei, cursor, csr_src);

    const int ablk = (N_NODES + 3) / 4;

    // layer 1
    aggregate_bf<false><<<ablk, 256, 0, stream>>>((const unsigned*)xb, (unsigned*)aggb,
                                                  row_start, csr_src, nullptr, nullptr);
    fused_layer<<<FBLK, 256, 0, stream>>>(
        aggb, (const bf16x8*)(wfrag + 0 * 16384), (const bf16x8*)(wfrag + 1 * 16384),
        b1a, b1b, hb, psum, psq, N_NODES);
    reduce_stats<<<RED_NB, 256, 0, stream>>>(psum, psq, ps2);
    bn_finalize<<<1, 256, 0, stream>>>(ps2, g1, be1, scale1, shift1);

    // layer 2 (BN1+ReLU fused into aggregate)
    aggregate_bf<true><<<ablk, 256, 0, stream>>>((const unsigned*)hb, (unsigned*)aggb,
                                                 row_start, csr_src, scale1, shift1);
    fused_layer<<<FBLK, 256, 0, stream>>>(
        aggb, (const bf16x8*)(wfrag + 2 * 16384), (const bf16x8*)(wfrag + 3 * 16384),
        b2a, b2b, hb, psum, psq, N_NODES);
    reduce_stats<<<RED_NB, 256, 0, stream>>>(psum, psq, ps2);
    bn_finalize<<<1, 256, 0, stream>>>(ps2, g2, be2, scale2, shift2);
    bn_pool<<<N_GRAPHS, 256, 0, stream>>>(hb, scale2, shift2, gs, pooled);

    final_gemm<<<(N_GRAPHS * N_CLASSES + 255) / 256, 256, 0, stream>>>(pooled, Wo, bo,
                                                                       (float*)d_out);
}

// Round 10
// 272.393 us; speedup vs baseline: 1.7516x; 1.1240x over previous
//
#include <hip/hip_runtime.h>

typedef __attribute__((ext_vector_type(8))) short bf16x8;
typedef __attribute__((ext_vector_type(4))) float f32x4;
typedef __attribute__((ext_vector_type(2))) float f32x2;
typedef __attribute__((ext_vector_type(2))) unsigned u32x2;

#define N_NODES 50000
#define N_EDGES 800000
#define DIM 128
#define N_GRAPHS 128
#define N_CLASSES 10
#define BN_EPS 1e-5f
#define FBLK ((N_NODES + 63) / 64)        // 782
#define NPART (FBLK * 4)                  // 3128 stat-partial rows
#define RED_NB 64
#define RED_ROWS ((NPART + RED_NB - 1) / RED_NB)   // 49

#define NBUCK 196                         // dst buckets of 256 nodes (50000>>8 = 195 max)
#define BCAP 32                           // LDS bin depth
#define FILL_NB 200
#define FILL_PER (N_EDGES / FILL_NB)      // 4000
#define BMAX 6144                         // max bucket size (mean 4096, +32 sigma)

static __device__ __forceinline__ unsigned short f2bf(float f) {
    unsigned u = __float_as_uint(f);
    u += 0x7FFF + ((u >> 16) & 1);   // round-to-nearest-even
    return (unsigned short)(u >> 16);
}
static __device__ __forceinline__ float bf_lo(unsigned u) { return __uint_as_float(u << 16); }
static __device__ __forceinline__ float bf_hi(unsigned u) { return __uint_as_float(u & 0xffff0000u); }
static __device__ __forceinline__ unsigned packbf(float a, float b) {
    return (unsigned)f2bf(a) | ((unsigned)f2bf(b) << 16);
}

// ---- x (f32) -> xb (bf16 packed) ----
__global__ __launch_bounds__(256) void cvt_x(const f32x2* __restrict__ x,
                                             unsigned* __restrict__ xb, int n) {
    int t = blockIdx.x * 256 + threadIdx.x;
    if (t < n) { f32x2 v = x[t]; xb[t] = packbf(v[0], v[1]); }
}

// ---- CSR build stage 1: per-bucket counts via LDS histogram (39k global atomics) ----
__global__ __launch_bounds__(256) void bucket_count(const int* __restrict__ ei,
                                                    int* __restrict__ gbcnt) {
    __shared__ int cnt[NBUCK];
    int tid = threadIdx.x;
    if (tid < NBUCK) cnt[tid] = 0;
    __syncthreads();
    int e0 = blockIdx.x * FILL_PER;
    for (int c = tid; c < FILL_PER; c += 256) {
        int dst = ei[N_EDGES + e0 + c];
        atomicAdd(&cnt[dst >> 8], 1);
    }
    __syncthreads();
    if (tid < NBUCK) atomicAdd(&gbcnt[tid], cnt[tid]);
}

// ---- CSR build stage 2: scan 196 bucket counts; init cursors ----
__global__ __launch_bounds__(256) void bucket_scan(const int* __restrict__ gbcnt,
                                                   int* __restrict__ boff,
                                                   int* __restrict__ gcur) {
    __shared__ int buf[256];
    int t = threadIdx.x;
    int v = (t < NBUCK) ? gbcnt[t] : 0;
    buf[t] = v;
    __syncthreads();
#pragma unroll
    for (int off = 1; off < 256; off <<= 1) {
        int u = (t >= off) ? buf[t - off] : 0;
        __syncthreads();
        buf[t] += u;
        __syncthreads();
    }
    if (t < NBUCK) { int ex = buf[t] - v; boff[t] = ex; gcur[t] = ex; }
    if (t == 0) boff[NBUCK] = N_EDGES;
}

// ---- CSR build stage 3: bin edges into bucket regions via LDS, 64B-run flushes ----
// packed word: src(16b) | dstLow8(bits 16..23)   [N_NODES < 2^16]
__global__ __launch_bounds__(256) void bucket_fill(const int* __restrict__ ei,
                                                   int* __restrict__ gcur,
                                                   unsigned* __restrict__ gbuf) {
    __shared__ unsigned bins[NBUCK * BCAP];   // 25 KB
    __shared__ int bcnt[NBUCK];
    int tid = threadIdx.x;
    if (tid < NBUCK) bcnt[tid] = 0;
    __syncthreads();
    int e0 = blockIdx.x * FILL_PER;
    for (int c = 0; c < FILL_PER; c += 256) {
        int idx = c + tid;
        if (idx < FILL_PER) {
            int e = e0 + idx;
            int src = ei[e];
            int dst = ei[N_EDGES + e];
            int b = dst >> 8;
            unsigned w = (unsigned)src | ((unsigned)(dst & 255) << 16);
            int slot = atomicAdd(&bcnt[b], 1);
            if (slot < BCAP) bins[b * BCAP + slot] = w;
            else { int p = atomicAdd(&gcur[b], 1); gbuf[p] = w; }   // rare overflow
        }
        __syncthreads();
        if (tid < NBUCK) {
            int cc = bcnt[tid]; if (cc > BCAP) cc = BCAP;
            int nf = cc & ~15;                 // flush 16-entry (64B) runs
            if (nf) {
                int base = atomicAdd(&gcur[tid], nf);
                for (int i = 0; i < nf; ++i) gbuf[base + i] = bins[tid * BCAP + i];
                int rem = cc - nf;
                for (int i = 0; i < rem; ++i) bins[tid * BCAP + i] = bins[tid * BCAP + nf + i];
                bcnt[tid] = rem;
            } else {
                bcnt[tid] = cc;
            }
        }
        __syncthreads();
    }
    if (tid < NBUCK) {                         // drain
        int cc = bcnt[tid]; if (cc > BCAP) cc = BCAP;
        if (cc) {
            int base = atomicAdd(&gcur[tid], cc);
            for (int i = 0; i < cc; ++i) gbuf[base + i] = bins[tid * BCAP + i];
        }
    }
}

// ---- CSR build stage 4: per-bucket in-LDS sort -> row_start + ushort csr ----
__global__ __launch_bounds__(256) void csr_build(const unsigned* __restrict__ gbuf,
                                                 const int* __restrict__ boff,
                                                 unsigned short* __restrict__ csr16,
                                                 int* __restrict__ row_start) {
    __shared__ unsigned ent[BMAX];            // 24 KB
    __shared__ unsigned short csl[BMAX];      // 12 KB
    __shared__ int cnt[256], c2[256], offs[256];
    int b = blockIdx.x, t = threadIdx.x;
    int base = boff[b], n = boff[b + 1] - base;
    for (int i = t; i < n; i += 256) ent[i] = gbuf[base + i];
    cnt[t] = 0; c2[t] = 0;
    __syncthreads();
    for (int i = t; i < n; i += 256) atomicAdd(&cnt[(ent[i] >> 16) & 255], 1);
    __syncthreads();
    int v = cnt[t];
    offs[t] = v;
    __syncthreads();
#pragma unroll
    for (int off = 1; off < 256; off <<= 1) {
        int u = (t >= off) ? offs[t - off] : 0;
        __syncthreads();
        offs[t] += u;
        __syncthreads();
    }
    int excl = offs[t] - v;
    int node = b * 256 + t;
    if (node < N_NODES) row_start[node] = base + excl;
    if (b == NBUCK - 1 && t == 0) row_start[N_NODES] = N_EDGES;
    __syncthreads();
    offs[t] = excl;
    __syncthreads();
    for (int i = t; i < n; i += 256) {
        unsigned w = ent[i];
        int d = (w >> 16) & 255;
        int r = atomicAdd(&c2[d], 1);
        csl[offs[d] + r] = (unsigned short)(w & 0xffffu);
    }
    __syncthreads();
    for (int i = t; i < n; i += 256) csr16[base + i] = csl[i];
}

// ---- graph segment starts via binary search (batch is sorted) ----
__global__ __launch_bounds__(256) void graph_starts(const int* __restrict__ batch,
                                                    int* __restrict__ gs) {
    int g = blockIdx.x * 256 + threadIdx.x;
    if (g > N_GRAPHS) return;
    int lo = 0, hi = N_NODES;
    while (lo < hi) {
        int mid = (lo + hi) >> 1;
        if (batch[mid] < g) lo = mid + 1; else hi = mid;
    }
    gs[g] = lo;
}

// ---- gather-sum aggregation on bf16 features; BN=true applies relu(f*sc+sh) ----
template <bool BN>
__global__ __launch_bounds__(256) void aggregate_bf(const unsigned* __restrict__ F,
                                                    unsigned* __restrict__ out,
                                                    const int* __restrict__ row_start,
                                                    const unsigned short* __restrict__ csr16,
                                                    const float* __restrict__ scale,
                                                    const float* __restrict__ shift) {
    int wave = threadIdx.x >> 6, lane = threadIdx.x & 63;
    int v = blockIdx.x * 4 + wave;
    if (v >= N_NODES) return;
    float sc0 = 0.f, sc1 = 0.f, sh0 = 0.f, sh1 = 0.f;
    if (BN) {
        f32x2 s2 = ((const f32x2*)scale)[lane];
        f32x2 h2 = ((const f32x2*)shift)[lane];
        sc0 = s2[0]; sc1 = s2[1]; sh0 = h2[0]; sh1 = h2[1];
    }
    unsigned u = F[(size_t)v * 64 + lane];
    float a0 = bf_lo(u), a1 = bf_hi(u);
    if (BN) { a0 = fmaxf(a0 * sc0 + sh0, 0.f); a1 = fmaxf(a1 * sc1 + sh1, 0.f); }
    int e = row_start[v], end = row_start[v + 1];
    for (; e + 3 < end; e += 4) {
        unsigned ua = F[(size_t)csr16[e] * 64 + lane];
        unsigned ub = F[(size_t)csr16[e + 1] * 64 + lane];
        unsigned uc = F[(size_t)csr16[e + 2] * 64 + lane];
        unsigned ud = F[(size_t)csr16[e + 3] * 64 + lane];
        float p0 = bf_lo(ua), p1 = bf_hi(ua), q0 = bf_lo(ub), q1 = bf_hi(ub);
        float r0 = bf_lo(uc), r1 = bf_hi(uc), s0 = bf_lo(ud), s1 = bf_hi(ud);
        if (BN) {
            p0 = fmaxf(p0 * sc0 + sh0, 0.f); p1 = fmaxf(p1 * sc1 + sh1, 0.f);
            q0 = fmaxf(q0 * sc0 + sh0, 0.f); q1 = fmaxf(q1 * sc1 + sh1, 0.f);
            r0 = fmaxf(r0 * sc0 + sh0, 0.f); r1 = fmaxf(r1 * sc1 + sh1, 0.f);
            s0 = fmaxf(s0 * sc0 + sh0, 0.f); s1 = fmaxf(s1 * sc1 + sh1, 0.f);
        }
        a0 += (p0 + q0) + (r0 + s0);
        a1 += (p1 + q1) + (r1 + s1);
    }
    for (; e < end; ++e) {
        unsigned ua = F[(size_t)csr16[e] * 64 + lane];
        float p0 = bf_lo(ua), p1 = bf_hi(ua);
        if (BN) { p0 = fmaxf(p0 * sc0 + sh0, 0.f); p1 = fmaxf(p1 * sc1 + sh1, 0.f); }
        a0 += p0; a1 += p1;
    }
    out[(size_t)v * 64 + lane] = packbf(a0, a1);
}

// ---- prep: permute W (f32 [128][128]) into bf16 B-fragment layout ----
__global__ __launch_bounds__(256) void prep_w(const float* __restrict__ W0,
                                              const float* __restrict__ W1,
                                              const float* __restrict__ W2,
                                              const float* __restrict__ W3,
                                              unsigned short* __restrict__ wf) {
    int t = blockIdx.x * 256 + threadIdx.x;
    if (t >= 4 * 16384) return;
    int m = t >> 14, rem = t & 16383;
    int e = rem & 7, lane = (rem >> 3) & 63, fi = rem >> 9;
    int ks = fi & 3, n = fi >> 2;
    int col = n * 16 + (lane & 15);
    int k = ks * 32 + ((lane >> 4) << 3) + e;
    const float* W = (m == 0) ? W0 : (m == 1) ? W1 : (m == 2) ? W2 : W3;
    wf[t] = f2bf(W[k * DIM + col]);
}

// ---- fused GIN layer: h = relu(A@Wa + ba) @ Wb + bb; per-wave stat partials ----
__global__ __launch_bounds__(256, 3) void fused_layer(
        const unsigned short* __restrict__ A,
        const bf16x8* __restrict__ wfA_g,
        const bf16x8* __restrict__ wfB_g,
        const float* __restrict__ bias_a,
        const float* __restrict__ bias_b,
        unsigned short* __restrict__ out,
        float* __restrict__ psum,
        float* __restrict__ psq, int M) {
    __shared__ bf16x8 wfS[2048];
    __shared__ unsigned short mid[8192];

    int tid = threadIdx.x;
    int w = tid >> 6, lane = tid & 63;
    int cl = lane & 15, kq = lane >> 4;
    int rblk = blockIdx.x * 64;

    bf16x8 wb[8];
#pragma unroll
    for (int i = 0; i < 8; ++i) wb[i] = wfB_g[i * 256 + tid];

#pragma unroll
    for (int i = 0; i < 8; ++i) wfS[i * 256 + tid] = wfA_g[i * 256 + tid];

    int arow = rblk + w * 16 + cl;
    if (arow >= M) arow = M - 1;
    bf16x8 af[4];
    const unsigned short* Ap = A + (size_t)arow * DIM + kq * 8;
#pragma unroll
    for (int ks = 0; ks < 4; ++ks) af[ks] = *(const bf16x8*)(Ap + ks * 32);

    __syncthreads();

    f32x4 acc[8];
#pragma unroll
    for (int n = 0; n < 8; ++n) acc[n] = f32x4{0.f, 0.f, 0.f, 0.f};
#pragma unroll
    for (int n = 0; n < 8; ++n)
#pragma unroll
        for (int ks = 0; ks < 4; ++ks)
            acc[n] = __builtin_amdgcn_mfma_f32_16x16x32_bf16(af[ks], wfS[(n * 4 + ks) * 64 + lane],
                                                             acc[n], 0, 0, 0);

#pragma unroll
    for (int n = 0; n < 8; ++n) {
        int col = n * 16 + cl;
        float b = bias_a[col];
#pragma unroll
        for (int r = 0; r < 4; ++r) {
            int rl = w * 16 + kq * 4 + r;
            float v = fmaxf(acc[n][r] + b, 0.f);
            mid[(rl * DIM + col) ^ ((rl & 7) << 3)] = f2bf(v);
        }
    }
    __syncthreads();

#pragma unroll
    for (int i = 0; i < 8; ++i) wfS[i * 256 + tid] = wb[i];

    bf16x8 af2[4];
    {
        int rl = w * 16 + cl;
        int sw = (cl & 7) << 3;
#pragma unroll
        for (int ks = 0; ks < 4; ++ks)
            af2[ks] = *(const bf16x8*)(mid + ((rl * DIM + kq * 8 + ks * 32) ^ sw));
    }
    __syncthreads();

    f32x4 acc2[8];
#pragma unroll
    for (int n = 0; n < 8; ++n) acc2[n] = f32x4{0.f, 0.f, 0.f, 0.f};
#pragma unroll
    for (int n = 0; n < 8; ++n)
#pragma unroll
        for (int ks = 0; ks < 4; ++ks)
            acc2[n] = __builtin_amdgcn_mfma_f32_16x16x32_bf16(af2[ks], wfS[(n * 4 + ks) * 64 + lane],
                                                              acc2[n], 0, 0, 0);

    int prow = blockIdx.x * 4 + w;
#pragma unroll
    for (int n = 0; n < 8; ++n) {
        int col = n * 16 + cl;
        float b = bias_b[col];
        float s = 0.f, q = 0.f;
#pragma unroll
        for (int r = 0; r < 4; ++r) {
            int rl = w * 16 + kq * 4 + r;
            float v = acc2[n][r] + b;
            if (rblk + rl < M) { s += v; q += v * v; }
            mid[(rl * DIM + col) ^ ((rl & 7) << 3)] = f2bf(v);
        }
        s += __shfl_xor(s, 16, 64);
        s += __shfl_xor(s, 32, 64);
        q += __shfl_xor(q, 16, 64);
        q += __shfl_xor(q, 32, 64);
        if (kq == 0) {
            psum[(size_t)prow * DIM + col] = s;
            psq[(size_t)prow * DIM + col] = q;
        }
    }

    {
        int r4 = lane >> 4, c = lane & 15;
#pragma unroll
        for (int rb = 0; rb < 4; ++rb) {
            int rl = w * 16 + rb * 4 + r4;
            int grow = rblk + rl;
            bf16x8 v = *(const bf16x8*)(mid + ((rl * DIM + c * 8) ^ ((rl & 7) << 3)));
            if (grow < M) *(bf16x8*)(out + (size_t)grow * DIM + c * 8) = v;
        }
    }
}

// ---- stats reduction stage 1 ----
__global__ __launch_bounds__(256) void reduce_stats(const float* __restrict__ psum,
                                                    const float* __restrict__ psq,
                                                    float* __restrict__ ps2) {
    int b = blockIdx.x, t = threadIdx.x;
    int c = t & 127;
    const float* src = (t < 128) ? psum : psq;
    int r0 = b * RED_ROWS;
    int r1 = min(NPART, r0 + RED_ROWS);
    float acc = 0.f;
    for (int r = r0; r < r1; ++r) acc += src[(size_t)r * DIM + c];
    ps2[(size_t)b * 256 + t] = acc;
}

// ---- BN finalize ----
__global__ __launch_bounds__(256) void bn_finalize(const float* __restrict__ ps2,
                                                   const float* __restrict__ g,
                                                   const float* __restrict__ be,
                                                   float* __restrict__ scale,
                                                   float* __restrict__ shift) {
    __shared__ float sums[128], sqs[128];
    int t = threadIdx.x;
    int c = t & 127;
    float acc = 0.f;
#pragma unroll 4
    for (int r = 0; r < RED_NB; ++r) acc += ps2[(size_t)r * 256 + t];
    if (t < 128) sums[c] = acc; else sqs[c] = acc;
    __syncthreads();
    if (t < 128) {
        const float invN = 1.0f / (float)N_NODES;
        float mu = sums[c] * invN;
        float var = sqs[c] * invN - mu * mu;
        float rs = rsqrtf(var + BN_EPS) * g[c];
        scale[c] = rs;
        shift[c] = be[c] - mu * rs;
    }
}

// ---- BN apply + ReLU + segmented pool ----
__global__ __launch_bounds__(256) void bn_pool(const unsigned short* __restrict__ h,
                                               const float* __restrict__ scale,
                                               const float* __restrict__ shift,
                                               const int* __restrict__ gs,
                                               float* __restrict__ pooled) {
    int g = blockIdx.x;
    int t = threadIdx.x;
    int c4 = t & 31;
    int rs = t >> 5;
    int r0 = gs[g], r1 = gs[g + 1];
    f32x4 sc = ((const f32x4*)scale)[c4];
    f32x4 sh = ((const f32x4*)shift)[c4];
    f32x4 acc = f32x4{0.f, 0.f, 0.f, 0.f};
    for (int r = r0 + rs; r < r1; r += 8) {
        u32x2 u = *(const u32x2*)(h + (size_t)r * DIM + c4 * 4);
        float f0 = bf_lo(u[0]), f1 = bf_hi(u[0]), f2 = bf_lo(u[1]), f3 = bf_hi(u[1]);
        acc[0] += fmaxf(f0 * sc[0] + sh[0], 0.f);
        acc[1] += fmaxf(f1 * sc[1] + sh[1], 0.f);
        acc[2] += fmaxf(f2 * sc[2] + sh[2], 0.f);
        acc[3] += fmaxf(f3 * sc[3] + sh[3], 0.f);
    }
    __shared__ f32x4 red[256];
    red[t] = acc;
    __syncthreads();
#pragma unroll
    for (int off = 128; off >= 32; off >>= 1) {
        if (t < off) red[t] += red[t + off];
        __syncthreads();
    }
    if (t < 32) ((f32x4*)pooled)[g * 32 + c4] = red[t];
}

// ---- final: out[g][c] = pooled[g] . Wo[:,c] + bo[c] ----
__global__ __launch_bounds__(256) void final_gemm(const float* __restrict__ pooled,
                                                  const float* __restrict__ Wo,
                                                  const float* __restrict__ bo,
                                                  float* __restrict__ out) {
    int t = blockIdx.x * 256 + threadIdx.x;
    if (t >= N_GRAPHS * N_CLASSES) return;
    int g = t / N_CLASSES, c = t - g * N_CLASSES;
    float s = bo[c];
    const float* p = pooled + (size_t)g * DIM;
#pragma unroll 4
    for (int k = 0; k < DIM; ++k) s += p[k] * Wo[k * N_CLASSES + c];
    out[t] = s;
}

extern "C" void kernel_launch(void* const* d_in, const int* in_sizes, int n_in,
                              void* d_out, int out_size, void* d_ws, size_t ws_size,
                              hipStream_t stream) {
    const float* x   = (const float*)d_in[0];
    const int* ei    = (const int*)d_in[1];   // harness: integer -> int32
    const int* batch = (const int*)d_in[2];
    const float* W1a = (const float*)d_in[3];
    const float* b1a = (const float*)d_in[4];
    const float* W1b = (const float*)d_in[5];
    const float* b1b = (const float*)d_in[6];
    const float* g1  = (const float*)d_in[7];
    const float* be1 = (const float*)d_in[8];
    const float* W2a = (const float*)d_in[9];
    const float* b2a = (const float*)d_in[10];
    const float* W2b = (const float*)d_in[11];
    const float* b2b = (const float*)d_in[12];
    const float* g2  = (const float*)d_in[13];
    const float* be2 = (const float*)d_in[14];
    const float* Wo  = (const float*)d_in[15];
    const float* bo  = (const float*)d_in[16];

    char* ws = (char*)d_ws;
    const size_t NBH = (size_t)N_NODES * DIM * 2;   // 12.8 MB bf16 features
    unsigned short* xb   = (unsigned short*)ws;
    unsigned short* aggb = (unsigned short*)(ws + NBH);
    unsigned short* hb   = (unsigned short*)(ws + 2 * NBH);
    unsigned short* wfrag = (unsigned short*)(ws + 3 * NBH);   // 128 KB
    float* psum = (float*)(ws + 3 * NBH + 4 * 16384 * 2);      // NPART*128
    float* psq  = psum + (size_t)NPART * DIM;
    float* ps2  = psq + (size_t)NPART * DIM;       // RED_NB*256
    float* pooled  = ps2 + RED_NB * 256;           // 128*128
    float* scale1  = pooled + N_GRAPHS * DIM;
    float* shift1  = scale1 + 128;
    float* scale2  = scale1 + 256;
    float* shift2  = scale1 + 384;
    int* gs        = (int*)(shift2 + 128);         // N_GRAPHS+1
    int* gbcnt     = gs + N_GRAPHS + 1;            // NBUCK
    int* boff      = gbcnt + NBUCK;                // NBUCK+1
    int* gcur      = boff + NBUCK + 1;             // NBUCK
    int* row_start = gcur + NBUCK;                 // N_NODES+1
    unsigned* gbuf = (unsigned*)(row_start + N_NODES + 1);     // N_EDGES u32
    unsigned short* csr16 = (unsigned short*)(gbuf + N_EDGES); // N_EDGES ushort

    hipMemsetAsync(gbcnt, 0, NBUCK * 4, stream);

    const int nv2 = N_NODES * 64;  // f32x2 count
    cvt_x<<<(nv2 + 255) / 256, 256, 0, stream>>>((const f32x2*)x, (unsigned*)xb, nv2);
    prep_w<<<256, 256, 0, stream>>>(W1a, W1b, W2a, W2b, wfrag);
    graph_starts<<<1, 256, 0, stream>>>(batch, gs);

    // CSR build: bucket count -> scan -> LDS-binned fill -> per-bucket LDS sort
    bucket_count<<<FILL_NB, 256, 0, stream>>>(ei, gbcnt);
    bucket_scan<<<1, 256, 0, stream>>>(gbcnt, boff, gcur);
    bucket_fill<<<FILL_NB, 256, 0, stream>>>(ei, gcur, gbuf);
    csr_build<<<NBUCK, 256, 0, stream>>>(gbuf, boff, csr16, row_start);

    const int ablk = (N_NODES + 3) / 4;

    // layer 1
    aggregate_bf<false><<<ablk, 256, 0, stream>>>((const unsigned*)xb, (unsigned*)aggb,
                                                  row_start, csr16, nullptr, nullptr);
    fused_layer<<<FBLK, 256, 0, stream>>>(
        aggb, (const bf16x8*)(wfrag + 0 * 16384), (const bf16x8*)(wfrag + 1 * 16384),
        b1a, b1b, hb, psum, psq, N_NODES);
    reduce_stats<<<RED_NB, 256, 0, stream>>>(psum, psq, ps2);
    bn_finalize<<<1, 256, 0, stream>>>(ps2, g1, be1, scale1, shift1);

    // layer 2 (BN1+ReLU fused into aggregate)
    aggregate_bf<true><<<ablk, 256, 0, stream>>>((const unsigned*)hb, (unsigned*)aggb,
                                                 row_start, csr16, scale1, shift1);
    fused_layer<<<FBLK, 256, 0, stream>>>(
        aggb, (const bf16x8*)(wfrag + 2 * 16384), (const bf16x8*)(wfrag + 3 * 16384),
        b2a, b2b, hb, psum, psq, N_NODES);
    reduce_stats<<<RED_NB, 256, 0, stream>>>(psum, psq, ps2);
    bn_finalize<<<1, 256, 0, stream>>>(ps2, g2, be2, scale2, shift2);
    bn_pool<<<N_GRAPHS, 256, 0, stream>>>(hb, scale2, shift2, gs, pooled);

    final_gemm<<<(N_GRAPHS * N_CLASSES + 255) / 256, 256, 0, stream>>>(pooled, Wo, bo,
                                                                       (float*)d_out);
}

// Round 11
// 251.602 us; speedup vs baseline: 1.8964x; 1.0826x over previous
//
#include <hip/hip_runtime.h>

typedef __attribute__((ext_vector_type(8))) short bf16x8;
typedef __attribute__((ext_vector_type(4))) float f32x4;
typedef __attribute__((ext_vector_type(2))) float f32x2;
typedef __attribute__((ext_vector_type(2))) unsigned u32x2;

#define N_NODES 50000
#define N_EDGES 800000
#define DIM 128
#define N_GRAPHS 128
#define N_CLASSES 10
#define BN_EPS 1e-5f
#define FBLK ((N_NODES + 63) / 64)        // 782
#define NPART (FBLK * 4)                  // 3128 stat-partial rows
#define RED_NB 64
#define RED_ROWS ((NPART + RED_NB - 1) / RED_NB)   // 49

#define NBUCK 196                         // dst buckets of 256 nodes
#define FILL_NB 400
#define FILL_PER (N_EDGES / FILL_NB)      // 2000
#define BMAX 6144                         // max bucket size (mean 4096, +32 sigma)

static __device__ __forceinline__ unsigned short f2bf(float f) {
    unsigned u = __float_as_uint(f);
    u += 0x7FFF + ((u >> 16) & 1);   // round-to-nearest-even
    return (unsigned short)(u >> 16);
}
static __device__ __forceinline__ float bf_lo(unsigned u) { return __uint_as_float(u << 16); }
static __device__ __forceinline__ float bf_hi(unsigned u) { return __uint_as_float(u & 0xffff0000u); }
static __device__ __forceinline__ unsigned packbf(float a, float b) {
    return (unsigned)f2bf(a) | ((unsigned)f2bf(b) << 16);
}

// ---- x (f32) -> xb (bf16 packed) ----
__global__ __launch_bounds__(256) void cvt_x(const f32x2* __restrict__ x,
                                             unsigned* __restrict__ xb, int n) {
    int t = blockIdx.x * 256 + threadIdx.x;
    if (t < n) { f32x2 v = x[t]; xb[t] = packbf(v[0], v[1]); }
}

// ---- CSR build stage 1: per-bucket counts via LDS histogram ----
__global__ __launch_bounds__(256) void bucket_count(const int* __restrict__ ei,
                                                    int* __restrict__ gbcnt) {
    __shared__ int cnt[NBUCK];
    int tid = threadIdx.x;
    if (tid < NBUCK) cnt[tid] = 0;
    __syncthreads();
    int e0 = blockIdx.x * FILL_PER;
    for (int c = tid; c < FILL_PER; c += 256) {
        int dst = ei[N_EDGES + e0 + c];
        atomicAdd(&cnt[dst >> 8], 1);
    }
    __syncthreads();
    if (tid < NBUCK) atomicAdd(&gbcnt[tid], cnt[tid]);
}

// ---- CSR build stage 2: scan 196 bucket counts; init cursors ----
__global__ __launch_bounds__(256) void bucket_scan(const int* __restrict__ gbcnt,
                                                   int* __restrict__ boff,
                                                   int* __restrict__ gcur) {
    __shared__ int buf[256];
    int t = threadIdx.x;
    int v = (t < NBUCK) ? gbcnt[t] : 0;
    buf[t] = v;
    __syncthreads();
#pragma unroll
    for (int off = 1; off < 256; off <<= 1) {
        int u = (t >= off) ? buf[t - off] : 0;
        __syncthreads();
        buf[t] += u;
        __syncthreads();
    }
    if (t < NBUCK) { int ex = buf[t] - v; boff[t] = ex; gcur[t] = ex; }
    if (t == 0) boff[NBUCK] = N_EDGES;
}

// ---- CSR build stage 3: block-local counting sort by bucket, coalesced run writes ----
// packed word: src(16b) | dstLow8(16..23) | bucket(24..31)
__global__ __launch_bounds__(256) void bucket_fill(const int* __restrict__ ei,
                                                   int* __restrict__ gcur,
                                                   unsigned* __restrict__ gbuf) {
    __shared__ unsigned ent[FILL_PER];   // 8 KB
    __shared__ unsigned srt[FILL_PER];   // 8 KB
    __shared__ int cnt[256], c2[256], lofs[256], gbase[256];
    int tid = threadIdx.x;
    int e0 = blockIdx.x * FILL_PER;
    cnt[tid] = 0; c2[tid] = 0;
    __syncthreads();
    for (int i = tid; i < FILL_PER; i += 256) {
        int src = ei[e0 + i];
        int dst = ei[N_EDGES + e0 + i];
        ent[i] = (unsigned)src | ((unsigned)(dst & 255) << 16) | ((unsigned)(dst >> 8) << 24);
        atomicAdd(&cnt[dst >> 8], 1);
    }
    __syncthreads();
    int v = cnt[tid];
    lofs[tid] = v;
    __syncthreads();
#pragma unroll
    for (int off = 1; off < 256; off <<= 1) {
        int u = (tid >= off) ? lofs[tid - off] : 0;
        __syncthreads();
        lofs[tid] += u;
        __syncthreads();
    }
    int excl = lofs[tid] - v;
    lofs[tid] = excl;                    // own-slot rewrite (safe: scan complete)
    if (tid < NBUCK && v > 0) gbase[tid] = atomicAdd(&gcur[tid], v);
    __syncthreads();
    for (int i = tid; i < FILL_PER; i += 256) {
        unsigned w = ent[i];
        int b = w >> 24;
        int r = atomicAdd(&c2[b], 1);
        srt[lofs[b] + r] = w;
    }
    __syncthreads();
    // sorted array -> global: consecutive threads hit consecutive addrs within runs
    for (int i = tid; i < FILL_PER; i += 256) {
        unsigned w = srt[i];
        int b = w >> 24;
        gbuf[gbase[b] + (i - lofs[b])] = w;
    }
}

// ---- CSR build stage 4: per-bucket in-LDS sort -> row_start + ushort csr ----
__global__ __launch_bounds__(256) void csr_build(const unsigned* __restrict__ gbuf,
                                                 const int* __restrict__ boff,
                                                 unsigned short* __restrict__ csr16,
                                                 int* __restrict__ row_start) {
    __shared__ unsigned ent[BMAX];            // 24 KB
    __shared__ unsigned short csl[BMAX];      // 12 KB
    __shared__ int cnt[256], c2[256], offs[256];
    int b = blockIdx.x, t = threadIdx.x;
    int base = boff[b], n = boff[b + 1] - base;
    for (int i = t; i < n; i += 256) ent[i] = gbuf[base + i];
    cnt[t] = 0; c2[t] = 0;
    __syncthreads();
    for (int i = t; i < n; i += 256) atomicAdd(&cnt[(ent[i] >> 16) & 255], 1);
    __syncthreads();
    int v = cnt[t];
    offs[t] = v;
    __syncthreads();
#pragma unroll
    for (int off = 1; off < 256; off <<= 1) {
        int u = (t >= off) ? offs[t - off] : 0;
        __syncthreads();
        offs[t] += u;
        __syncthreads();
    }
    int excl = offs[t] - v;
    int node = b * 256 + t;
    if (node < N_NODES) row_start[node] = base + excl;
    if (b == NBUCK - 1 && t == 0) row_start[N_NODES] = N_EDGES;
    __syncthreads();
    offs[t] = excl;
    __syncthreads();
    for (int i = t; i < n; i += 256) {
        unsigned w = ent[i];
        int d = (w >> 16) & 255;
        int r = atomicAdd(&c2[d], 1);
        csl[offs[d] + r] = (unsigned short)(w & 0xffffu);
    }
    __syncthreads();
    for (int i = t; i < n; i += 256) csr16[base + i] = csl[i];
}

// ---- graph segment starts via binary search (batch is sorted) ----
__global__ __launch_bounds__(256) void graph_starts(const int* __restrict__ batch,
                                                    int* __restrict__ gs) {
    int g = blockIdx.x * 256 + threadIdx.x;
    if (g > N_GRAPHS) return;
    int lo = 0, hi = N_NODES;
    while (lo < hi) {
        int mid = (lo + hi) >> 1;
        if (batch[mid] < g) lo = mid + 1; else hi = mid;
    }
    gs[g] = lo;
}

// ---- gather-sum aggregation on bf16 features; BN=true applies relu(f*sc+sh) ----
template <bool BN>
__global__ __launch_bounds__(256) void aggregate_bf(const unsigned* __restrict__ F,
                                                    unsigned* __restrict__ out,
                                                    const int* __restrict__ row_start,
                                                    const unsigned short* __restrict__ csr16,
                                                    const float* __restrict__ scale,
                                                    const float* __restrict__ shift) {
    int wave = threadIdx.x >> 6, lane = threadIdx.x & 63;
    int v = blockIdx.x * 4 + wave;
    if (v >= N_NODES) return;
    float sc0 = 0.f, sc1 = 0.f, sh0 = 0.f, sh1 = 0.f;
    if (BN) {
        f32x2 s2 = ((const f32x2*)scale)[lane];
        f32x2 h2 = ((const f32x2*)shift)[lane];
        sc0 = s2[0]; sc1 = s2[1]; sh0 = h2[0]; sh1 = h2[1];
    }
    unsigned u = F[(size_t)v * 64 + lane];
    float a0 = bf_lo(u), a1 = bf_hi(u);
    if (BN) { a0 = fmaxf(a0 * sc0 + sh0, 0.f); a1 = fmaxf(a1 * sc1 + sh1, 0.f); }
    int e = row_start[v], end = row_start[v + 1];
    for (; e + 3 < end; e += 4) {
        unsigned ua = F[(size_t)csr16[e] * 64 + lane];
        unsigned ub = F[(size_t)csr16[e + 1] * 64 + lane];
        unsigned uc = F[(size_t)csr16[e + 2] * 64 + lane];
        unsigned ud = F[(size_t)csr16[e + 3] * 64 + lane];
        float p0 = bf_lo(ua), p1 = bf_hi(ua), q0 = bf_lo(ub), q1 = bf_hi(ub);
        float r0 = bf_lo(uc), r1 = bf_hi(uc), s0 = bf_lo(ud), s1 = bf_hi(ud);
        if (BN) {
            p0 = fmaxf(p0 * sc0 + sh0, 0.f); p1 = fmaxf(p1 * sc1 + sh1, 0.f);
            q0 = fmaxf(q0 * sc0 + sh0, 0.f); q1 = fmaxf(q1 * sc1 + sh1, 0.f);
            r0 = fmaxf(r0 * sc0 + sh0, 0.f); r1 = fmaxf(r1 * sc1 + sh1, 0.f);
            s0 = fmaxf(s0 * sc0 + sh0, 0.f); s1 = fmaxf(s1 * sc1 + sh1, 0.f);
        }
        a0 += (p0 + q0) + (r0 + s0);
        a1 += (p1 + q1) + (r1 + s1);
    }
    for (; e < end; ++e) {
        unsigned ua = F[(size_t)csr16[e] * 64 + lane];
        float p0 = bf_lo(ua), p1 = bf_hi(ua);
        if (BN) { p0 = fmaxf(p0 * sc0 + sh0, 0.f); p1 = fmaxf(p1 * sc1 + sh1, 0.f); }
        a0 += p0; a1 += p1;
    }
    out[(size_t)v * 64 + lane] = packbf(a0, a1);
}

// ---- prep: permute W (f32 [128][128]) into bf16 B-fragment layout ----
__global__ __launch_bounds__(256) void prep_w(const float* __restrict__ W0,
                                              const float* __restrict__ W1,
                                              const float* __restrict__ W2,
                                              const float* __restrict__ W3,
                                              unsigned short* __restrict__ wf) {
    int t = blockIdx.x * 256 + threadIdx.x;
    if (t >= 4 * 16384) return;
    int m = t >> 14, rem = t & 16383;
    int e = rem & 7, lane = (rem >> 3) & 63, fi = rem >> 9;
    int ks = fi & 3, n = fi >> 2;
    int col = n * 16 + (lane & 15);
    int k = ks * 32 + ((lane >> 4) << 3) + e;
    const float* W = (m == 0) ? W0 : (m == 1) ? W1 : (m == 2) ? W2 : W3;
    wf[t] = f2bf(W[k * DIM + col]);
}

// ---- fused GIN layer: h = relu(A@Wa + ba) @ Wb + bb; per-wave stat partials ----
__global__ __launch_bounds__(256, 3) void fused_layer(
        const unsigned short* __restrict__ A,
        const bf16x8* __restrict__ wfA_g,
        const bf16x8* __restrict__ wfB_g,
        const float* __restrict__ bias_a,
        const float* __restrict__ bias_b,
        unsigned short* __restrict__ out,
        float* __restrict__ psum,
        float* __restrict__ psq, int M) {
    __shared__ bf16x8 wfS[2048];
    __shared__ unsigned short mid[8192];

    int tid = threadIdx.x;
    int w = tid >> 6, lane = tid & 63;
    int cl = lane & 15, kq = lane >> 4;
    int rblk = blockIdx.x * 64;

    bf16x8 wb[8];
#pragma unroll
    for (int i = 0; i < 8; ++i) wb[i] = wfB_g[i * 256 + tid];

#pragma unroll
    for (int i = 0; i < 8; ++i) wfS[i * 256 + tid] = wfA_g[i * 256 + tid];

    int arow = rblk + w * 16 + cl;
    if (arow >= M) arow = M - 1;
    bf16x8 af[4];
    const unsigned short* Ap = A + (size_t)arow * DIM + kq * 8;
#pragma unroll
    for (int ks = 0; ks < 4; ++ks) af[ks] = *(const bf16x8*)(Ap + ks * 32);

    __syncthreads();

    f32x4 acc[8];
#pragma unroll
    for (int n = 0; n < 8; ++n) acc[n] = f32x4{0.f, 0.f, 0.f, 0.f};
#pragma unroll
    for (int n = 0; n < 8; ++n)
#pragma unroll
        for (int ks = 0; ks < 4; ++ks)
            acc[n] = __builtin_amdgcn_mfma_f32_16x16x32_bf16(af[ks], wfS[(n * 4 + ks) * 64 + lane],
                                                             acc[n], 0, 0, 0);

#pragma unroll
    for (int n = 0; n < 8; ++n) {
        int col = n * 16 + cl;
        float b = bias_a[col];
#pragma unroll
        for (int r = 0; r < 4; ++r) {
            int rl = w * 16 + kq * 4 + r;
            float v = fmaxf(acc[n][r] + b, 0.f);
            mid[(rl * DIM + col) ^ ((rl & 7) << 3)] = f2bf(v);
        }
    }
    __syncthreads();

#pragma unroll
    for (int i = 0; i < 8; ++i) wfS[i * 256 + tid] = wb[i];

    bf16x8 af2[4];
    {
        int rl = w * 16 + cl;
        int sw = (cl & 7) << 3;
#pragma unroll
        for (int ks = 0; ks < 4; ++ks)
            af2[ks] = *(const bf16x8*)(mid + ((rl * DIM + kq * 8 + ks * 32) ^ sw));
    }
    __syncthreads();

    f32x4 acc2[8];
#pragma unroll
    for (int n = 0; n < 8; ++n) acc2[n] = f32x4{0.f, 0.f, 0.f, 0.f};
#pragma unroll
    for (int n = 0; n < 8; ++n)
#pragma unroll
        for (int ks = 0; ks < 4; ++ks)
            acc2[n] = __builtin_amdgcn_mfma_f32_16x16x32_bf16(af2[ks], wfS[(n * 4 + ks) * 64 + lane],
                                                              acc2[n], 0, 0, 0);

    int prow = blockIdx.x * 4 + w;
#pragma unroll
    for (int n = 0; n < 8; ++n) {
        int col = n * 16 + cl;
        float b = bias_b[col];
        float s = 0.f, q = 0.f;
#pragma unroll
        for (int r = 0; r < 4; ++r) {
            int rl = w * 16 + kq * 4 + r;
            float v = acc2[n][r] + b;
            if (rblk + rl < M) { s += v; q += v * v; }
            mid[(rl * DIM + col) ^ ((rl & 7) << 3)] = f2bf(v);
        }
        s += __shfl_xor(s, 16, 64);
        s += __shfl_xor(s, 32, 64);
        q += __shfl_xor(q, 16, 64);
        q += __shfl_xor(q, 32, 64);
        if (kq == 0) {
            psum[(size_t)prow * DIM + col] = s;
            psq[(size_t)prow * DIM + col] = q;
        }
    }

    {
        int r4 = lane >> 4, c = lane & 15;
#pragma unroll
        for (int rb = 0; rb < 4; ++rb) {
            int rl = w * 16 + rb * 4 + r4;
            int grow = rblk + rl;
            bf16x8 v = *(const bf16x8*)(mid + ((rl * DIM + c * 8) ^ ((rl & 7) << 3)));
            if (grow < M) *(bf16x8*)(out + (size_t)grow * DIM + c * 8) = v;
        }
    }
}

// ---- stats reduction stage 1 ----
__global__ __launch_bounds__(256) void reduce_stats(const float* __restrict__ psum,
                                                    const float* __restrict__ psq,
                                                    float* __restrict__ ps2) {
    int b = blockIdx.x, t = threadIdx.x;
    int c = t & 127;
    const float* src = (t < 128) ? psum : psq;
    int r0 = b * RED_ROWS;
    int r1 = min(NPART, r0 + RED_ROWS);
    float acc = 0.f;
    for (int r = r0; r < r1; ++r) acc += src[(size_t)r * DIM + c];
    ps2[(size_t)b * 256 + t] = acc;
}

// ---- BN finalize ----
__global__ __launch_bounds__(256) void bn_finalize(const float* __restrict__ ps2,
                                                   const float* __restrict__ g,
                                                   const float* __restrict__ be,
                                                   float* __restrict__ scale,
                                                   float* __restrict__ shift) {
    __shared__ float sums[128], sqs[128];
    int t = threadIdx.x;
    int c = t & 127;
    float acc = 0.f;
#pragma unroll 4
    for (int r = 0; r < RED_NB; ++r) acc += ps2[(size_t)r * 256 + t];
    if (t < 128) sums[c] = acc; else sqs[c] = acc;
    __syncthreads();
    if (t < 128) {
        const float invN = 1.0f / (float)N_NODES;
        float mu = sums[c] * invN;
        float var = sqs[c] * invN - mu * mu;
        float rs = rsqrtf(var + BN_EPS) * g[c];
        scale[c] = rs;
        shift[c] = be[c] - mu * rs;
    }
}

// ---- BN apply + ReLU + segmented pool ----
__global__ __launch_bounds__(256) void bn_pool(const unsigned short* __restrict__ h,
                                               const float* __restrict__ scale,
                                               const float* __restrict__ shift,
                                               const int* __restrict__ gs,
                                               float* __restrict__ pooled) {
    int g = blockIdx.x;
    int t = threadIdx.x;
    int c4 = t & 31;
    int rs = t >> 5;
    int r0 = gs[g], r1 = gs[g + 1];
    f32x4 sc = ((const f32x4*)scale)[c4];
    f32x4 sh = ((const f32x4*)shift)[c4];
    f32x4 acc = f32x4{0.f, 0.f, 0.f, 0.f};
    for (int r = r0 + rs; r < r1; r += 8) {
        u32x2 u = *(const u32x2*)(h + (size_t)r * DIM + c4 * 4);
        float f0 = bf_lo(u[0]), f1 = bf_hi(u[0]), f2 = bf_lo(u[1]), f3 = bf_hi(u[1]);
        acc[0] += fmaxf(f0 * sc[0] + sh[0], 0.f);
        acc[1] += fmaxf(f1 * sc[1] + sh[1], 0.f);
        acc[2] += fmaxf(f2 * sc[2] + sh[2], 0.f);
        acc[3] += fmaxf(f3 * sc[3] + sh[3], 0.f);
    }
    __shared__ f32x4 red[256];
    red[t] = acc;
    __syncthreads();
#pragma unroll
    for (int off = 128; off >= 32; off >>= 1) {
        if (t < off) red[t] += red[t + off];
        __syncthreads();
    }
    if (t < 32) ((f32x4*)pooled)[g * 32 + c4] = red[t];
}

// ---- final: out[g][c] = pooled[g] . Wo[:,c] + bo[c] ----
__global__ __launch_bounds__(256) void final_gemm(const float* __restrict__ pooled,
                                                  const float* __restrict__ Wo,
                                                  const float* __restrict__ bo,
                                                  float* __restrict__ out) {
    int t = blockIdx.x * 256 + threadIdx.x;
    if (t >= N_GRAPHS * N_CLASSES) return;
    int g = t / N_CLASSES, c = t - g * N_CLASSES;
    float s = bo[c];
    const float* p = pooled + (size_t)g * DIM;
#pragma unroll 4
    for (int k = 0; k < DIM; ++k) s += p[k] * Wo[k * N_CLASSES + c];
    out[t] = s;
}

extern "C" void kernel_launch(void* const* d_in, const int* in_sizes, int n_in,
                              void* d_out, int out_size, void* d_ws, size_t ws_size,
                              hipStream_t stream) {
    const float* x   = (const float*)d_in[0];
    const int* ei    = (const int*)d_in[1];   // harness: integer -> int32
    const int* batch = (const int*)d_in[2];
    const float* W1a = (const float*)d_in[3];
    const float* b1a = (const float*)d_in[4];
    const float* W1b = (const float*)d_in[5];
    const float* b1b = (const float*)d_in[6];
    const float* g1  = (const float*)d_in[7];
    const float* be1 = (const float*)d_in[8];
    const float* W2a = (const float*)d_in[9];
    const float* b2a = (const float*)d_in[10];
    const float* W2b = (const float*)d_in[11];
    const float* b2b = (const float*)d_in[12];
    const float* g2  = (const float*)d_in[13];
    const float* be2 = (const float*)d_in[14];
    const float* Wo  = (const float*)d_in[15];
    const float* bo  = (const float*)d_in[16];

    char* ws = (char*)d_ws;
    const size_t NBH = (size_t)N_NODES * DIM * 2;   // 12.8 MB bf16 features
    unsigned short* xb   = (unsigned short*)ws;
    unsigned short* aggb = (unsigned short*)(ws + NBH);
    unsigned short* hb   = (unsigned short*)(ws + 2 * NBH);
    unsigned short* wfrag = (unsigned short*)(ws + 3 * NBH);   // 128 KB
    float* psum = (float*)(ws + 3 * NBH + 4 * 16384 * 2);      // NPART*128
    float* psq  = psum + (size_t)NPART * DIM;
    float* ps2  = psq + (size_t)NPART * DIM;       // RED_NB*256
    float* pooled  = ps2 + RED_NB * 256;           // 128*128
    float* scale1  = pooled + N_GRAPHS * DIM;
    float* shift1  = scale1 + 128;
    float* scale2  = scale1 + 256;
    float* shift2  = scale1 + 384;
    int* gs        = (int*)(shift2 + 128);         // N_GRAPHS+1
    int* gbcnt     = gs + N_GRAPHS + 1;            // NBUCK
    int* boff      = gbcnt + NBUCK;                // NBUCK+1
    int* gcur      = boff + NBUCK + 1;             // NBUCK
    int* row_start = gcur + NBUCK;                 // N_NODES+1
    unsigned* gbuf = (unsigned*)(row_start + N_NODES + 1);     // N_EDGES u32
    unsigned short* csr16 = (unsigned short*)(gbuf + N_EDGES); // N_EDGES ushort

    hipMemsetAsync(gbcnt, 0, NBUCK * 4, stream);

    const int nv2 = N_NODES * 64;  // f32x2 count
    cvt_x<<<(nv2 + 255) / 256, 256, 0, stream>>>((const f32x2*)x, (unsigned*)xb, nv2);
    prep_w<<<256, 256, 0, stream>>>(W1a, W1b, W2a, W2b, wfrag);
    graph_starts<<<1, 256, 0, stream>>>(batch, gs);

    // CSR build: bucket count -> scan -> block-local counting sort -> per-bucket sort
    bucket_count<<<FILL_NB, 256, 0, stream>>>(ei, gbcnt);
    bucket_scan<<<1, 256, 0, stream>>>(gbcnt, boff, gcur);
    bucket_fill<<<FILL_NB, 256, 0, stream>>>(ei, gcur, gbuf);
    csr_build<<<NBUCK, 256, 0, stream>>>(gbuf, boff, csr16, row_start);

    const int ablk = (N_NODES + 3) / 4;

    // layer 1
    aggregate_bf<false><<<ablk, 256, 0, stream>>>((const unsigned*)xb, (unsigned*)aggb,
                                                  row_start, csr16, nullptr, nullptr);
    fused_layer<<<FBLK, 256, 0, stream>>>(
        aggb, (const bf16x8*)(wfrag + 0 * 16384), (const bf16x8*)(wfrag + 1 * 16384),
        b1a, b1b, hb, psum, psq, N_NODES);
    reduce_stats<<<RED_NB, 256, 0, stream>>>(psum, psq, ps2);
    bn_finalize<<<1, 256, 0, stream>>>(ps2, g1, be1, scale1, shift1);

    // layer 2 (BN1+ReLU fused into aggregate)
    aggregate_bf<true><<<ablk, 256, 0, stream>>>((const unsigned*)hb, (unsigned*)aggb,
                                                 row_start, csr16, scale1, shift1);
    fused_layer<<<FBLK, 256, 0, stream>>>(
        aggb, (const bf16x8*)(wfrag + 2 * 16384), (const bf16x8*)(wfrag + 3 * 16384),
        b2a, b2b, hb, psum, psq, N_NODES);
    reduce_stats<<<RED_NB, 256, 0, stream>>>(psum, psq, ps2);
    bn_finalize<<<1, 256, 0, stream>>>(ps2, g2, be2, scale2, shift2);
    bn_pool<<<N_GRAPHS, 256, 0, stream>>>(hb, scale2, shift2, gs, pooled);

    final_gemm<<<(N_GRAPHS * N_CLASSES + 255) / 256, 256, 0, stream>>>(pooled, Wo, bo,
                                                                       (float*)d_out);
}

// Round 12
// 240.711 us; speedup vs baseline: 1.9822x; 1.0452x over previous
//
#include <hip/hip_runtime.h>

typedef __attribute__((ext_vector_type(8))) short bf16x8;
typedef __attribute__((ext_vector_type(4))) float f32x4;
typedef __attribute__((ext_vector_type(2))) float f32x2;
typedef __attribute__((ext_vector_type(2))) unsigned u32x2;

#define N_NODES 50000
#define N_EDGES 800000
#define DIM 128
#define N_GRAPHS 128
#define N_CLASSES 10
#define BN_EPS 1e-5f
#define FBLK ((N_NODES + 63) / 64)        // 782
#define NPART (FBLK * 4)                  // 3128 stat-partial rows
#define RED_NB 64
#define RED_ROWS ((NPART + RED_NB - 1) / RED_NB)   // 49

#define NBUCK 196                         // dst buckets of 256 nodes
#define FILL_NB 400
#define FILL_PER (N_EDGES / FILL_NB)      // 2000
#define BMAX 6144                         // max bucket size (mean 4096, +32 sigma)

#define CVT_NB (N_NODES * 64 / 256)       // 12500
#define PREPW_NB 256

static __device__ __forceinline__ unsigned short f2bf(float f) {
    unsigned u = __float_as_uint(f);
    u += 0x7FFF + ((u >> 16) & 1);   // round-to-nearest-even
    return (unsigned short)(u >> 16);
}
static __device__ __forceinline__ float bf_lo(unsigned u) { return __uint_as_float(u << 16); }
static __device__ __forceinline__ float bf_hi(unsigned u) { return __uint_as_float(u & 0xffff0000u); }
static __device__ __forceinline__ unsigned packbf(float a, float b) {
    return (unsigned)f2bf(a) | ((unsigned)f2bf(b) << 16);
}

// ---- fused prep: x->bf16 | W permute | graph segment starts (block-partitioned) ----
__global__ __launch_bounds__(256) void prep_all(const f32x2* __restrict__ x,
                                                unsigned* __restrict__ xb,
                                                const float* __restrict__ W0,
                                                const float* __restrict__ W1,
                                                const float* __restrict__ W2,
                                                const float* __restrict__ W3,
                                                unsigned short* __restrict__ wf,
                                                const int* __restrict__ batch,
                                                int* __restrict__ gs) {
    int b = blockIdx.x, tid = threadIdx.x;
    if (b < CVT_NB) {
        int t = b * 256 + tid;
        f32x2 v = x[t];
        xb[t] = packbf(v[0], v[1]);
    } else if (b < CVT_NB + PREPW_NB) {
        int t = (b - CVT_NB) * 256 + tid;
        int m = t >> 14, rem = t & 16383;
        int e = rem & 7, lane = (rem >> 3) & 63, fi = rem >> 9;
        int ks = fi & 3, n = fi >> 2;
        int col = n * 16 + (lane & 15);
        int k = ks * 32 + ((lane >> 4) << 3) + e;
        const float* W = (m == 0) ? W0 : (m == 1) ? W1 : (m == 2) ? W2 : W3;
        wf[t] = f2bf(W[k * DIM + col]);
    } else {
        int g = tid;
        if (g > N_GRAPHS) return;
        int lo = 0, hi = N_NODES;
        while (lo < hi) {
            int mid = (lo + hi) >> 1;
            if (batch[mid] < g) lo = mid + 1; else hi = mid;
        }
        gs[g] = lo;
    }
}

// ---- CSR build stage 1: per-bucket counts via LDS histogram ----
__global__ __launch_bounds__(256) void bucket_count(const int* __restrict__ ei,
                                                    int* __restrict__ gbcnt) {
    __shared__ int cnt[NBUCK];
    int tid = threadIdx.x;
    if (tid < NBUCK) cnt[tid] = 0;
    __syncthreads();
    int e0 = blockIdx.x * FILL_PER;
    for (int c = tid; c < FILL_PER; c += 256) {
        int dst = ei[N_EDGES + e0 + c];
        atomicAdd(&cnt[dst >> 8], 1);
    }
    __syncthreads();
    if (tid < NBUCK) atomicAdd(&gbcnt[tid], cnt[tid]);
}

// ---- CSR build stage 2: scan 196 bucket counts; init cursors ----
__global__ __launch_bounds__(256) void bucket_scan(const int* __restrict__ gbcnt,
                                                   int* __restrict__ boff,
                                                   int* __restrict__ gcur) {
    __shared__ int buf[256];
    int t = threadIdx.x;
    int v = (t < NBUCK) ? gbcnt[t] : 0;
    buf[t] = v;
    __syncthreads();
#pragma unroll
    for (int off = 1; off < 256; off <<= 1) {
        int u = (t >= off) ? buf[t - off] : 0;
        __syncthreads();
        buf[t] += u;
        __syncthreads();
    }
    if (t < NBUCK) { int ex = buf[t] - v; boff[t] = ex; gcur[t] = ex; }
    if (t == 0) boff[NBUCK] = N_EDGES;
}

// ---- CSR build stage 3: block-local counting sort by bucket, coalesced run writes ----
__global__ __launch_bounds__(256) void bucket_fill(const int* __restrict__ ei,
                                                   int* __restrict__ gcur,
                                                   unsigned* __restrict__ gbuf) {
    __shared__ unsigned ent[FILL_PER];
    __shared__ unsigned srt[FILL_PER];
    __shared__ int cnt[256], c2[256], lofs[256], gbase[256];
    int tid = threadIdx.x;
    int e0 = blockIdx.x * FILL_PER;
    cnt[tid] = 0; c2[tid] = 0;
    __syncthreads();
    for (int i = tid; i < FILL_PER; i += 256) {
        int src = ei[e0 + i];
        int dst = ei[N_EDGES + e0 + i];
        ent[i] = (unsigned)src | ((unsigned)(dst & 255) << 16) | ((unsigned)(dst >> 8) << 24);
        atomicAdd(&cnt[dst >> 8], 1);
    }
    __syncthreads();
    int v = cnt[tid];
    lofs[tid] = v;
    __syncthreads();
#pragma unroll
    for (int off = 1; off < 256; off <<= 1) {
        int u = (tid >= off) ? lofs[tid - off] : 0;
        __syncthreads();
        lofs[tid] += u;
        __syncthreads();
    }
    int excl = lofs[tid] - v;
    lofs[tid] = excl;
    if (tid < NBUCK && v > 0) gbase[tid] = atomicAdd(&gcur[tid], v);
    __syncthreads();
    for (int i = tid; i < FILL_PER; i += 256) {
        unsigned w = ent[i];
        int b = w >> 24;
        int r = atomicAdd(&c2[b], 1);
        srt[lofs[b] + r] = w;
    }
    __syncthreads();
    for (int i = tid; i < FILL_PER; i += 256) {
        unsigned w = srt[i];
        int b = w >> 24;
        gbuf[gbase[b] + (i - lofs[b])] = w;
    }
}

// ---- CSR build stage 4: per-bucket in-LDS sort -> row_start + ushort csr ----
__global__ __launch_bounds__(256) void csr_build(const unsigned* __restrict__ gbuf,
                                                 const int* __restrict__ boff,
                                                 unsigned short* __restrict__ csr16,
                                                 int* __restrict__ row_start) {
    __shared__ unsigned ent[BMAX];
    __shared__ unsigned short csl[BMAX];
    __shared__ int cnt[256], c2[256], offs[256];
    int b = blockIdx.x, t = threadIdx.x;
    int base = boff[b], n = boff[b + 1] - base;
    for (int i = t; i < n; i += 256) ent[i] = gbuf[base + i];
    cnt[t] = 0; c2[t] = 0;
    __syncthreads();
    for (int i = t; i < n; i += 256) atomicAdd(&cnt[(ent[i] >> 16) & 255], 1);
    __syncthreads();
    int v = cnt[t];
    offs[t] = v;
    __syncthreads();
#pragma unroll
    for (int off = 1; off < 256; off <<= 1) {
        int u = (t >= off) ? offs[t - off] : 0;
        __syncthreads();
        offs[t] += u;
        __syncthreads();
    }
    int excl = offs[t] - v;
    int node = b * 256 + t;
    if (node < N_NODES) row_start[node] = base + excl;
    if (b == NBUCK - 1 && t == 0) row_start[N_NODES] = N_EDGES;
    __syncthreads();
    offs[t] = excl;
    __syncthreads();
    for (int i = t; i < n; i += 256) {
        unsigned w = ent[i];
        int d = (w >> 16) & 255;
        int r = atomicAdd(&c2[d], 1);
        csl[offs[d] + r] = (unsigned short)(w & 0xffffu);
    }
    __syncthreads();
    for (int i = t; i < n; i += 256) csr16[base + i] = csl[i];
}

// ---- gather-sum aggregation: 8B/lane, half-waves process even/odd edges ----
// lane<32: even edges; lane>=32: odd edges; each lane covers 4 cols (u32x2)
template <bool BN>
__global__ __launch_bounds__(256) void aggregate_bf(const u32x2* __restrict__ F2,
                                                    u32x2* __restrict__ out,
                                                    const int* __restrict__ row_start,
                                                    const unsigned short* __restrict__ csr16,
                                                    const float* __restrict__ scale,
                                                    const float* __restrict__ shift) {
    int wave = threadIdx.x >> 6, lane = threadIdx.x & 63;
    int v = blockIdx.x * 4 + wave;
    if (v >= N_NODES) return;
    int half = lane >> 5;
    int c4 = lane & 31;            // u32x2 index within 256B row
    f32x4 sc, sh;
    if (BN) {
        sc = ((const f32x4*)scale)[c4];
        sh = ((const f32x4*)shift)[c4];
    }
    f32x4 acc = f32x4{0.f, 0.f, 0.f, 0.f};
    if (half == 0) {               // self term in half 0
        u32x2 u = F2[(size_t)v * 32 + c4];
        acc[0] = bf_lo(u[0]); acc[1] = bf_hi(u[0]);
        acc[2] = bf_lo(u[1]); acc[3] = bf_hi(u[1]);
        if (BN) {
#pragma unroll
            for (int k = 0; k < 4; ++k) acc[k] = fmaxf(acc[k] * sc[k] + sh[k], 0.f);
        }
    }
    int e0 = row_start[v];
    int n = row_start[v + 1] - e0;
    int i = half;
    for (; i + 2 < n; i += 4) {    // two edges per half per iter
        int s0 = csr16[e0 + i], s1 = csr16[e0 + i + 2];
        u32x2 ua = F2[(size_t)s0 * 32 + c4];
        u32x2 ub = F2[(size_t)s1 * 32 + c4];
        float p0 = bf_lo(ua[0]), p1 = bf_hi(ua[0]), p2 = bf_lo(ua[1]), p3 = bf_hi(ua[1]);
        float q0 = bf_lo(ub[0]), q1 = bf_hi(ub[0]), q2 = bf_lo(ub[1]), q3 = bf_hi(ub[1]);
        if (BN) {
            p0 = fmaxf(p0 * sc[0] + sh[0], 0.f); p1 = fmaxf(p1 * sc[1] + sh[1], 0.f);
            p2 = fmaxf(p2 * sc[2] + sh[2], 0.f); p3 = fmaxf(p3 * sc[3] + sh[3], 0.f);
            q0 = fmaxf(q0 * sc[0] + sh[0], 0.f); q1 = fmaxf(q1 * sc[1] + sh[1], 0.f);
            q2 = fmaxf(q2 * sc[2] + sh[2], 0.f); q3 = fmaxf(q3 * sc[3] + sh[3], 0.f);
        }
        acc[0] += p0 + q0; acc[1] += p1 + q1; acc[2] += p2 + q2; acc[3] += p3 + q3;
    }
    for (; i < n; i += 2) {
        int s = csr16[e0 + i];
        u32x2 ua = F2[(size_t)s * 32 + c4];
        float p0 = bf_lo(ua[0]), p1 = bf_hi(ua[0]), p2 = bf_lo(ua[1]), p3 = bf_hi(ua[1]);
        if (BN) {
            p0 = fmaxf(p0 * sc[0] + sh[0], 0.f); p1 = fmaxf(p1 * sc[1] + sh[1], 0.f);
            p2 = fmaxf(p2 * sc[2] + sh[2], 0.f); p3 = fmaxf(p3 * sc[3] + sh[3], 0.f);
        }
        acc[0] += p0; acc[1] += p1; acc[2] += p2; acc[3] += p3;
    }
    // combine halves
#pragma unroll
    for (int k = 0; k < 4; ++k) acc[k] += __shfl_xor(acc[k], 32, 64);
    if (half == 0) {
        u32x2 w;
        w[0] = packbf(acc[0], acc[1]);
        w[1] = packbf(acc[2], acc[3]);
        out[(size_t)v * 32 + c4] = w;
    }
}

// ---- fused GIN layer: h = relu(A@Wa + ba) @ Wb + bb; per-wave stat partials ----
__global__ __launch_bounds__(256, 3) void fused_layer(
        const unsigned short* __restrict__ A,
        const bf16x8* __restrict__ wfA_g,
        const bf16x8* __restrict__ wfB_g,
        const float* __restrict__ bias_a,
        const float* __restrict__ bias_b,
        unsigned short* __restrict__ out,
        float* __restrict__ psum,
        float* __restrict__ psq, int M) {
    __shared__ bf16x8 wfS[2048];
    __shared__ unsigned short mid[8192];

    int tid = threadIdx.x;
    int w = tid >> 6, lane = tid & 63;
    int cl = lane & 15, kq = lane >> 4;
    int rblk = blockIdx.x * 64;

    bf16x8 wb[8];
#pragma unroll
    for (int i = 0; i < 8; ++i) wb[i] = wfB_g[i * 256 + tid];

#pragma unroll
    for (int i = 0; i < 8; ++i) wfS[i * 256 + tid] = wfA_g[i * 256 + tid];

    int arow = rblk + w * 16 + cl;
    if (arow >= M) arow = M - 1;
    bf16x8 af[4];
    const unsigned short* Ap = A + (size_t)arow * DIM + kq * 8;
#pragma unroll
    for (int ks = 0; ks < 4; ++ks) af[ks] = *(const bf16x8*)(Ap + ks * 32);

    __syncthreads();

    f32x4 acc[8];
#pragma unroll
    for (int n = 0; n < 8; ++n) acc[n] = f32x4{0.f, 0.f, 0.f, 0.f};
#pragma unroll
    for (int n = 0; n < 8; ++n)
#pragma unroll
        for (int ks = 0; ks < 4; ++ks)
            acc[n] = __builtin_amdgcn_mfma_f32_16x16x32_bf16(af[ks], wfS[(n * 4 + ks) * 64 + lane],
                                                             acc[n], 0, 0, 0);

#pragma unroll
    for (int n = 0; n < 8; ++n) {
        int col = n * 16 + cl;
        float b = bias_a[col];
#pragma unroll
        for (int r = 0; r < 4; ++r) {
            int rl = w * 16 + kq * 4 + r;
            float v = fmaxf(acc[n][r] + b, 0.f);
            mid[(rl * DIM + col) ^ ((rl & 7) << 3)] = f2bf(v);
        }
    }
    __syncthreads();

#pragma unroll
    for (int i = 0; i < 8; ++i) wfS[i * 256 + tid] = wb[i];

    bf16x8 af2[4];
    {
        int rl = w * 16 + cl;
        int sw = (cl & 7) << 3;
#pragma unroll
        for (int ks = 0; ks < 4; ++ks)
            af2[ks] = *(const bf16x8*)(mid + ((rl * DIM + kq * 8 + ks * 32) ^ sw));
    }
    __syncthreads();

    f32x4 acc2[8];
#pragma unroll
    for (int n = 0; n < 8; ++n) acc2[n] = f32x4{0.f, 0.f, 0.f, 0.f};
#pragma unroll
    for (int n = 0; n < 8; ++n)
#pragma unroll
        for (int ks = 0; ks < 4; ++ks)
            acc2[n] = __builtin_amdgcn_mfma_f32_16x16x32_bf16(af2[ks], wfS[(n * 4 + ks) * 64 + lane],
                                                              acc2[n], 0, 0, 0);

    int prow = blockIdx.x * 4 + w;
#pragma unroll
    for (int n = 0; n < 8; ++n) {
        int col = n * 16 + cl;
        float b = bias_b[col];
        float s = 0.f, q = 0.f;
#pragma unroll
        for (int r = 0; r < 4; ++r) {
            int rl = w * 16 + kq * 4 + r;
            float v = acc2[n][r] + b;
            if (rblk + rl < M) { s += v; q += v * v; }
            mid[(rl * DIM + col) ^ ((rl & 7) << 3)] = f2bf(v);
        }
        s += __shfl_xor(s, 16, 64);
        s += __shfl_xor(s, 32, 64);
        q += __shfl_xor(q, 16, 64);
        q += __shfl_xor(q, 32, 64);
        if (kq == 0) {
            psum[(size_t)prow * DIM + col] = s;
            psq[(size_t)prow * DIM + col] = q;
        }
    }

    {
        int r4 = lane >> 4, c = lane & 15;
#pragma unroll
        for (int rb = 0; rb < 4; ++rb) {
            int rl = w * 16 + rb * 4 + r4;
            int grow = rblk + rl;
            bf16x8 v = *(const bf16x8*)(mid + ((rl * DIM + c * 8) ^ ((rl & 7) << 3)));
            if (grow < M) *(bf16x8*)(out + (size_t)grow * DIM + c * 8) = v;
        }
    }
}

// ---- stats reduction stage 1 ----
__global__ __launch_bounds__(256) void reduce_stats(const float* __restrict__ psum,
                                                    const float* __restrict__ psq,
                                                    float* __restrict__ ps2) {
    int b = blockIdx.x, t = threadIdx.x;
    int c = t & 127;
    const float* src = (t < 128) ? psum : psq;
    int r0 = b * RED_ROWS;
    int r1 = min(NPART, r0 + RED_ROWS);
    float acc = 0.f;
    for (int r = r0; r < r1; ++r) acc += src[(size_t)r * DIM + c];
    ps2[(size_t)b * 256 + t] = acc;
}

// ---- BN finalize ----
__global__ __launch_bounds__(256) void bn_finalize(const float* __restrict__ ps2,
                                                   const float* __restrict__ g,
                                                   const float* __restrict__ be,
                                                   float* __restrict__ scale,
                                                   float* __restrict__ shift) {
    __shared__ float sums[128], sqs[128];
    int t = threadIdx.x;
    int c = t & 127;
    float acc = 0.f;
#pragma unroll 4
    for (int r = 0; r < RED_NB; ++r) acc += ps2[(size_t)r * 256 + t];
    if (t < 128) sums[c] = acc; else sqs[c] = acc;
    __syncthreads();
    if (t < 128) {
        const float invN = 1.0f / (float)N_NODES;
        float mu = sums[c] * invN;
        float var = sqs[c] * invN - mu * mu;
        float rs = rsqrtf(var + BN_EPS) * g[c];
        scale[c] = rs;
        shift[c] = be[c] - mu * rs;
    }
}

// ---- BN apply + ReLU + segmented pool + classifier (one block per graph) ----
__global__ __launch_bounds__(256) void bn_pool_final(const unsigned short* __restrict__ h,
                                                     const float* __restrict__ scale,
                                                     const float* __restrict__ shift,
                                                     const int* __restrict__ gs,
                                                     const float* __restrict__ Wo,
                                                     const float* __restrict__ bo,
                                                     float* __restrict__ out) {
    int g = blockIdx.x;
    int t = threadIdx.x;
    int c4 = t & 31;
    int rs = t >> 5;
    int r0 = gs[g], r1 = gs[g + 1];
    f32x4 sc = ((const f32x4*)scale)[c4];
    f32x4 sh = ((const f32x4*)shift)[c4];
    f32x4 acc = f32x4{0.f, 0.f, 0.f, 0.f};
    for (int r = r0 + rs; r < r1; r += 8) {
        u32x2 u = *(const u32x2*)(h + (size_t)r * DIM + c4 * 4);
        float f0 = bf_lo(u[0]), f1 = bf_hi(u[0]), f2 = bf_lo(u[1]), f3 = bf_hi(u[1]);
        acc[0] += fmaxf(f0 * sc[0] + sh[0], 0.f);
        acc[1] += fmaxf(f1 * sc[1] + sh[1], 0.f);
        acc[2] += fmaxf(f2 * sc[2] + sh[2], 0.f);
        acc[3] += fmaxf(f3 * sc[3] + sh[3], 0.f);
    }
    __shared__ f32x4 red[256];
    __shared__ float pf[DIM];
    red[t] = acc;
    __syncthreads();
#pragma unroll
    for (int off = 128; off >= 32; off >>= 1) {
        if (t < off) red[t] += red[t + off];
        __syncthreads();
    }
    if (t < 32) {
        f32x4 r = red[t];
        pf[t * 4 + 0] = r[0]; pf[t * 4 + 1] = r[1];
        pf[t * 4 + 2] = r[2]; pf[t * 4 + 3] = r[3];
    }
    __syncthreads();
    if (t < N_CLASSES) {
        float s = bo[t];
#pragma unroll 8
        for (int k = 0; k < DIM; ++k) s += pf[k] * Wo[k * N_CLASSES + t];
        out[g * N_CLASSES + t] = s;
    }
}

extern "C" void kernel_launch(void* const* d_in, const int* in_sizes, int n_in,
                              void* d_out, int out_size, void* d_ws, size_t ws_size,
                              hipStream_t stream) {
    const float* x   = (const float*)d_in[0];
    const int* ei    = (const int*)d_in[1];   // harness: integer -> int32
    const int* batch = (const int*)d_in[2];
    const float* W1a = (const float*)d_in[3];
    const float* b1a = (const float*)d_in[4];
    const float* W1b = (const float*)d_in[5];
    const float* b1b = (const float*)d_in[6];
    const float* g1  = (const float*)d_in[7];
    const float* be1 = (const float*)d_in[8];
    const float* W2a = (const float*)d_in[9];
    const float* b2a = (const float*)d_in[10];
    const float* W2b = (const float*)d_in[11];
    const float* b2b = (const float*)d_in[12];
    const float* g2  = (const float*)d_in[13];
    const float* be2 = (const float*)d_in[14];
    const float* Wo  = (const float*)d_in[15];
    const float* bo  = (const float*)d_in[16];

    char* ws = (char*)d_ws;
    const size_t NBH = (size_t)N_NODES * DIM * 2;   // 12.8 MB bf16 features
    unsigned short* xb   = (unsigned short*)ws;
    unsigned short* aggb = (unsigned short*)(ws + NBH);
    unsigned short* hb   = (unsigned short*)(ws + 2 * NBH);
    unsigned short* wfrag = (unsigned short*)(ws + 3 * NBH);   // 128 KB
    float* psum = (float*)(ws + 3 * NBH + 4 * 16384 * 2);      // NPART*128
    float* psq  = psum + (size_t)NPART * DIM;
    float* ps2  = psq + (size_t)NPART * DIM;       // RED_NB*256
    float* scale1  = ps2 + RED_NB * 256;
    float* shift1  = scale1 + 128;
    float* scale2  = scale1 + 256;
    float* shift2  = scale1 + 384;
    int* gs        = (int*)(shift2 + 128);         // N_GRAPHS+1
    int* gbcnt     = gs + N_GRAPHS + 1;            // NBUCK
    int* boff      = gbcnt + NBUCK;                // NBUCK+1
    int* gcur      = boff + NBUCK + 1;             // NBUCK
    int* row_start = gcur + NBUCK;                 // N_NODES+1
    unsigned* gbuf = (unsigned*)(row_start + N_NODES + 1);     // N_EDGES u32
    unsigned short* csr16 = (unsigned short*)(gbuf + N_EDGES); // N_EDGES ushort

    hipMemsetAsync(gbcnt, 0, NBUCK * 4, stream);

    prep_all<<<CVT_NB + PREPW_NB + 1, 256, 0, stream>>>(
        (const f32x2*)x, (unsigned*)xb, W1a, W1b, W2a, W2b, wfrag, batch, gs);

    // CSR build: bucket count -> scan -> block-local counting sort -> per-bucket sort
    bucket_count<<<FILL_NB, 256, 0, stream>>>(ei, gbcnt);
    bucket_scan<<<1, 256, 0, stream>>>(gbcnt, boff, gcur);
    bucket_fill<<<FILL_NB, 256, 0, stream>>>(ei, gcur, gbuf);
    csr_build<<<NBUCK, 256, 0, stream>>>(gbuf, boff, csr16, row_start);

    const int ablk = (N_NODES + 3) / 4;

    // layer 1
    aggregate_bf<false><<<ablk, 256, 0, stream>>>((const u32x2*)xb, (u32x2*)aggb,
                                                  row_start, csr16, nullptr, nullptr);
    fused_layer<<<FBLK, 256, 0, stream>>>(
        aggb, (const bf16x8*)(wfrag + 0 * 16384), (const bf16x8*)(wfrag + 1 * 16384),
        b1a, b1b, hb, psum, psq, N_NODES);
    reduce_stats<<<RED_NB, 256, 0, stream>>>(psum, psq, ps2);
    bn_finalize<<<1, 256, 0, stream>>>(ps2, g1, be1, scale1, shift1);

    // layer 2 (BN1+ReLU fused into aggregate)
    aggregate_bf<true><<<ablk, 256, 0, stream>>>((const u32x2*)hb, (u32x2*)aggb,
                                                 row_start, csr16, scale1, shift1);
    fused_layer<<<FBLK, 256, 0, stream>>>(
        aggb, (const bf16x8*)(wfrag + 2 * 16384), (const bf16x8*)(wfrag + 3 * 16384),
        b2a, b2b, hb, psum, psq, N_NODES);
    reduce_stats<<<RED_NB, 256, 0, stream>>>(psum, psq, ps2);
    bn_finalize<<<1, 256, 0, stream>>>(ps2, g2, be2, scale2, shift2);

    bn_pool_final<<<N_GRAPHS, 256, 0, stream>>>(hb, scale2, shift2, gs, Wo, bo,
                                                (float*)d_out);
}

// Round 14
// 221.676 us; speedup vs baseline: 2.1524x; 1.0859x over previous
//
#include <hip/hip_runtime.h>

typedef __attribute__((ext_vector_type(8))) short bf16x8;
typedef __attribute__((ext_vector_type(4))) float f32x4;
typedef __attribute__((ext_vector_type(2))) float f32x2;
typedef __attribute__((ext_vector_type(2))) unsigned u32x2;

#define N_NODES 50000
#define N_EDGES 800000
#define DIM 128
#define N_GRAPHS 128
#define N_CLASSES 10
#define BN_EPS 1e-5f
#define FBLK ((N_NODES + 63) / 64)        // 782
#define NPART (FBLK * 4)                  // 3128 stat-partial rows
#define RED_NB 64
#define RED_ROWS ((NPART + RED_NB - 1) / RED_NB)   // 49

#define NBUCK 196                         // dst buckets of 256 nodes
#define FILL_NB 400
#define FILL_PER (N_EDGES / FILL_NB)      // 2000
#define BMAX 6144                         // max bucket size

#define CVT_NB (N_NODES * 64 / 256)       // 12500
#define PREPW_NB 256

static __device__ __forceinline__ unsigned short f2bf(float f) {
    unsigned u = __float_as_uint(f);
    u += 0x7FFF + ((u >> 16) & 1);   // round-to-nearest-even
    return (unsigned short)(u >> 16);
}
static __device__ __forceinline__ float bf_lo(unsigned u) { return __uint_as_float(u << 16); }
static __device__ __forceinline__ float bf_hi(unsigned u) { return __uint_as_float(u & 0xffff0000u); }
static __device__ __forceinline__ unsigned packbf(float a, float b) {
    return (unsigned)f2bf(a) | ((unsigned)f2bf(b) << 16);
}

// ---- fused prep: x->bf16 | W permute | graph starts | bucket_count ----
__global__ __launch_bounds__(256) void prep_all(const f32x2* __restrict__ x,
                                                unsigned* __restrict__ xb,
                                                const float* __restrict__ W0,
                                                const float* __restrict__ W1,
                                                const float* __restrict__ W2,
                                                const float* __restrict__ W3,
                                                unsigned short* __restrict__ wf,
                                                const int* __restrict__ batch,
                                                int* __restrict__ gs,
                                                const int* __restrict__ ei,
                                                int* __restrict__ gbcnt) {
    int b = blockIdx.x, tid = threadIdx.x;
    if (b < CVT_NB) {
        int t = b * 256 + tid;
        f32x2 v = x[t];
        xb[t] = packbf(v[0], v[1]);
    } else if (b < CVT_NB + PREPW_NB) {
        int t = (b - CVT_NB) * 256 + tid;
        int m = t >> 14, rem = t & 16383;
        int e = rem & 7, lane = (rem >> 3) & 63, fi = rem >> 9;
        int ks = fi & 3, n = fi >> 2;
        int col = n * 16 + (lane & 15);
        int k = ks * 32 + ((lane >> 4) << 3) + e;
        const float* W = (m == 0) ? W0 : (m == 1) ? W1 : (m == 2) ? W2 : W3;
        wf[t] = f2bf(W[k * DIM + col]);
    } else if (b < CVT_NB + PREPW_NB + FILL_NB) {
        __shared__ int cnt[NBUCK];
        if (tid < NBUCK) cnt[tid] = 0;
        __syncthreads();
        int e0 = (b - CVT_NB - PREPW_NB) * FILL_PER;
        for (int c = tid; c < FILL_PER; c += 256) {
            int dst = ei[N_EDGES + e0 + c];
            atomicAdd(&cnt[dst >> 8], 1);
        }
        __syncthreads();
        if (tid < NBUCK) atomicAdd(&gbcnt[tid], cnt[tid]);
    } else {
        int g = tid;
        if (g > N_GRAPHS) return;
        int lo = 0, hi = N_NODES;
        while (lo < hi) {
            int mid = (lo + hi) >> 1;
            if (batch[mid] < g) lo = mid + 1; else hi = mid;
        }
        gs[g] = lo;
    }
}

// ---- CSR build stage 2: scan 196 bucket counts; init cursors ----
__global__ __launch_bounds__(256) void bucket_scan(const int* __restrict__ gbcnt,
                                                   int* __restrict__ boff,
                                                   int* __restrict__ gcur) {
    __shared__ int buf[256];
    int t = threadIdx.x;
    int v = (t < NBUCK) ? gbcnt[t] : 0;
    buf[t] = v;
    __syncthreads();
#pragma unroll
    for (int off = 1; off < 256; off <<= 1) {
        int u = (t >= off) ? buf[t - off] : 0;
        __syncthreads();
        buf[t] += u;
        __syncthreads();
    }
    if (t < NBUCK) { int ex = buf[t] - v; boff[t] = ex; gcur[t] = ex; }
    if (t == 0) boff[NBUCK] = N_EDGES;
}

// ---- CSR build stage 3: block-local counting sort by bucket ----
__global__ __launch_bounds__(256) void bucket_fill(const int* __restrict__ ei,
                                                   int* __restrict__ gcur,
                                                   unsigned* __restrict__ gbuf) {
    __shared__ unsigned ent[FILL_PER];
    __shared__ unsigned srt[FILL_PER];
    __shared__ int cnt[256], c2[256], lofs[256], gbase[256];
    int tid = threadIdx.x;
    int e0 = blockIdx.x * FILL_PER;
    cnt[tid] = 0; c2[tid] = 0;
    __syncthreads();
    for (int i = tid; i < FILL_PER; i += 256) {
        int src = ei[e0 + i];
        int dst = ei[N_EDGES + e0 + i];
        ent[i] = (unsigned)src | ((unsigned)(dst & 255) << 16) | ((unsigned)(dst >> 8) << 24);
        atomicAdd(&cnt[dst >> 8], 1);
    }
    __syncthreads();
    int v = cnt[tid];
    lofs[tid] = v;
    __syncthreads();
#pragma unroll
    for (int off = 1; off < 256; off <<= 1) {
        int u = (tid >= off) ? lofs[tid - off] : 0;
        __syncthreads();
        lofs[tid] += u;
        __syncthreads();
    }
    int excl = lofs[tid] - v;
    lofs[tid] = excl;
    if (tid < NBUCK && v > 0) gbase[tid] = atomicAdd(&gcur[tid], v);
    __syncthreads();
    for (int i = tid; i < FILL_PER; i += 256) {
        unsigned w = ent[i];
        int b = w >> 24;
        int r = atomicAdd(&c2[b], 1);
        srt[lofs[b] + r] = w;
    }
    __syncthreads();
    for (int i = tid; i < FILL_PER; i += 256) {
        unsigned w = srt[i];
        int b = w >> 24;
        gbuf[gbase[b] + (i - lofs[b])] = w;
    }
}

// ---- CSR build stage 4: per-bucket in-LDS sort -> row_start + ushort csr ----
__global__ __launch_bounds__(256) void csr_build(const unsigned* __restrict__ gbuf,
                                                 const int* __restrict__ boff,
                                                 unsigned short* __restrict__ csr16,
                                                 int* __restrict__ row_start) {
    __shared__ unsigned ent[BMAX];
    __shared__ unsigned short csl[BMAX];
    __shared__ int cnt[256], c2[256], offs[256];
    int b = blockIdx.x, t = threadIdx.x;
    int base = boff[b], n = boff[b + 1] - base;
    for (int i = t; i < n; i += 256) ent[i] = gbuf[base + i];
    cnt[t] = 0; c2[t] = 0;
    __syncthreads();
    for (int i = t; i < n; i += 256) atomicAdd(&cnt[(ent[i] >> 16) & 255], 1);
    __syncthreads();
    int v = cnt[t];
    offs[t] = v;
    __syncthreads();
#pragma unroll
    for (int off = 1; off < 256; off <<= 1) {
        int u = (t >= off) ? offs[t - off] : 0;
        __syncthreads();
        offs[t] += u;
        __syncthreads();
    }
    int excl = offs[t] - v;
    int node = b * 256 + t;
    if (node < N_NODES) row_start[node] = base + excl;
    if (b == NBUCK - 1 && t == 0) row_start[N_NODES] = N_EDGES;
    __syncthreads();
    offs[t] = excl;
    __syncthreads();
    for (int i = t; i < n; i += 256) {
        unsigned w = ent[i];
        int d = (w >> 16) & 255;
        int r = atomicAdd(&c2[d], 1);
        csl[offs[d] + r] = (unsigned short)(w & 0xffffu);
    }
    __syncthreads();
    for (int i = t; i < n; i += 256) csr16[base + i] = csl[i];
}

// ---- gather-sum aggregation: lane-parallel index preload, UNIFORM loop (safe shfl) ----
// half 0: even edges (+self); half 1: odd edges; lane covers 4 cols (u32x2 load)
// All 64 lanes execute every __shfl together (loop bound n64 is wave-uniform);
// per-edge validity is handled by predicated accumulation AFTER the loads.
template <bool BN>
__global__ __launch_bounds__(256) void aggregate_bf(const u32x2* __restrict__ F2,
                                                    u32x2* __restrict__ out,
                                                    const int* __restrict__ row_start,
                                                    const unsigned short* __restrict__ csr16,
                                                    const float* __restrict__ scale,
                                                    const float* __restrict__ shift) {
    int wave = threadIdx.x >> 6, lane = threadIdx.x & 63;
    int v = blockIdx.x * 4 + wave;
    if (v >= N_NODES) return;
    int half = lane >> 5;
    int c4 = lane & 31;
    f32x4 sc, sh;
    if (BN) {
        sc = ((const f32x4*)scale)[c4];
        sh = ((const f32x4*)shift)[c4];
    }
    int e0 = row_start[v];
    int n = row_start[v + 1] - e0;
    // one coalesced 2B/lane load covers the first 64 edge indices
    int myidx = (lane < n) ? (int)csr16[e0 + lane] : 0;
    int n64 = (n < 64) ? n : 64;   // wave-uniform

    f32x4 a0 = f32x4{0.f, 0.f, 0.f, 0.f};
    f32x4 a1 = f32x4{0.f, 0.f, 0.f, 0.f};
    if (half == 0) {   // self term
        u32x2 u = F2[(size_t)v * 32 + c4];
        a0[0] = bf_lo(u[0]); a0[1] = bf_hi(u[0]);
        a0[2] = bf_lo(u[1]); a0[3] = bf_hi(u[1]);
        if (BN) {
#pragma unroll
            for (int k = 0; k < 4; ++k) a0[k] = fmaxf(a0[k] * sc[k] + sh[k], 0.f);
        }
    }

    for (int base = 0; base < n64; base += 8) {   // uniform trip count
        int j0 = base + half, j1 = j0 + 2, j2 = j0 + 4, j3 = j0 + 6;
        int s0 = __shfl(myidx, j0 & 63, 64);
        int s1 = __shfl(myidx, j1 & 63, 64);
        int s2 = __shfl(myidx, j2 & 63, 64);
        int s3 = __shfl(myidx, j3 & 63, 64);
        u32x2 ua = F2[(size_t)s0 * 32 + c4];
        u32x2 ub = F2[(size_t)s1 * 32 + c4];
        u32x2 uc = F2[(size_t)s2 * 32 + c4];
        u32x2 ud = F2[(size_t)s3 * 32 + c4];
        float p0 = bf_lo(ua[0]), p1 = bf_hi(ua[0]), p2 = bf_lo(ua[1]), p3 = bf_hi(ua[1]);
        float q0 = bf_lo(ub[0]), q1 = bf_hi(ub[0]), q2 = bf_lo(ub[1]), q3 = bf_hi(ub[1]);
        float r0 = bf_lo(uc[0]), r1 = bf_hi(uc[0]), r2 = bf_lo(uc[1]), r3 = bf_hi(uc[1]);
        float t0 = bf_lo(ud[0]), t1 = bf_hi(ud[0]), t2 = bf_lo(ud[1]), t3 = bf_hi(ud[1]);
        if (BN) {
            p0 = fmaxf(p0 * sc[0] + sh[0], 0.f); p1 = fmaxf(p1 * sc[1] + sh[1], 0.f);
            p2 = fmaxf(p2 * sc[2] + sh[2], 0.f); p3 = fmaxf(p3 * sc[3] + sh[3], 0.f);
            q0 = fmaxf(q0 * sc[0] + sh[0], 0.f); q1 = fmaxf(q1 * sc[1] + sh[1], 0.f);
            q2 = fmaxf(q2 * sc[2] + sh[2], 0.f); q3 = fmaxf(q3 * sc[3] + sh[3], 0.f);
            r0 = fmaxf(r0 * sc[0] + sh[0], 0.f); r1 = fmaxf(r1 * sc[1] + sh[1], 0.f);
            r2 = fmaxf(r2 * sc[2] + sh[2], 0.f); r3 = fmaxf(r3 * sc[3] + sh[3], 0.f);
            t0 = fmaxf(t0 * sc[0] + sh[0], 0.f); t1 = fmaxf(t1 * sc[1] + sh[1], 0.f);
            t2 = fmaxf(t2 * sc[2] + sh[2], 0.f); t3 = fmaxf(t3 * sc[3] + sh[3], 0.f);
        }
        if (j0 < n64) { a0[0] += p0; a0[1] += p1; a0[2] += p2; a0[3] += p3; }
        if (j1 < n64) { a0[0] += q0; a0[1] += q1; a0[2] += q2; a0[3] += q3; }
        if (j2 < n64) { a1[0] += r0; a1[1] += r1; a1[2] += r2; a1[3] += r3; }
        if (j3 < n64) { a1[0] += t0; a1[1] += t1; a1[2] += t2; a1[3] += t3; }
    }
    for (int j = 64 + half; j < n; j += 2) {   // rare: degree > 64 (direct loads, no shfl)
        int s = csr16[e0 + j];
        u32x2 ua = F2[(size_t)s * 32 + c4];
        float p0 = bf_lo(ua[0]), p1 = bf_hi(ua[0]), p2 = bf_lo(ua[1]), p3 = bf_hi(ua[1]);
        if (BN) {
            p0 = fmaxf(p0 * sc[0] + sh[0], 0.f); p1 = fmaxf(p1 * sc[1] + sh[1], 0.f);
            p2 = fmaxf(p2 * sc[2] + sh[2], 0.f); p3 = fmaxf(p3 * sc[3] + sh[3], 0.f);
        }
        a0[0] += p0; a0[1] += p1; a0[2] += p2; a0[3] += p3;
    }
#pragma unroll
    for (int k = 0; k < 4; ++k) a0[k] += a1[k];
#pragma unroll
    for (int k = 0; k < 4; ++k) a0[k] += __shfl_xor(a0[k], 32, 64);
    if (half == 0) {
        u32x2 w;
        w[0] = packbf(a0[0], a0[1]);
        w[1] = packbf(a0[2], a0[3]);
        out[(size_t)v * 32 + c4] = w;
    }
}

// ---- fused GIN layer: h = relu(A@Wa + ba) @ Wb + bb; per-wave stat partials ----
__global__ __launch_bounds__(256, 3) void fused_layer(
        const unsigned short* __restrict__ A,
        const bf16x8* __restrict__ wfA_g,
        const bf16x8* __restrict__ wfB_g,
        const float* __restrict__ bias_a,
        const float* __restrict__ bias_b,
        unsigned short* __restrict__ out,
        float* __restrict__ psum,
        float* __restrict__ psq, int M) {
    __shared__ bf16x8 wfS[2048];
    __shared__ unsigned short mid[8192];

    int tid = threadIdx.x;
    int w = tid >> 6, lane = tid & 63;
    int cl = lane & 15, kq = lane >> 4;
    int rblk = blockIdx.x * 64;

    bf16x8 wb[8];
#pragma unroll
    for (int i = 0; i < 8; ++i) wb[i] = wfB_g[i * 256 + tid];

#pragma unroll
    for (int i = 0; i < 8; ++i) wfS[i * 256 + tid] = wfA_g[i * 256 + tid];

    int arow = rblk + w * 16 + cl;
    if (arow >= M) arow = M - 1;
    bf16x8 af[4];
    const unsigned short* Ap = A + (size_t)arow * DIM + kq * 8;
#pragma unroll
    for (int ks = 0; ks < 4; ++ks) af[ks] = *(const bf16x8*)(Ap + ks * 32);

    __syncthreads();

    f32x4 acc[8];
#pragma unroll
    for (int n = 0; n < 8; ++n) acc[n] = f32x4{0.f, 0.f, 0.f, 0.f};
#pragma unroll
    for (int n = 0; n < 8; ++n)
#pragma unroll
        for (int ks = 0; ks < 4; ++ks)
            acc[n] = __builtin_amdgcn_mfma_f32_16x16x32_bf16(af[ks], wfS[(n * 4 + ks) * 64 + lane],
                                                             acc[n], 0, 0, 0);

#pragma unroll
    for (int n = 0; n < 8; ++n) {
        int col = n * 16 + cl;
        float b = bias_a[col];
#pragma unroll
        for (int r = 0; r < 4; ++r) {
            int rl = w * 16 + kq * 4 + r;
            float v = fmaxf(acc[n][r] + b, 0.f);
            mid[(rl * DIM + col) ^ ((rl & 7) << 3)] = f2bf(v);
        }
    }
    __syncthreads();

#pragma unroll
    for (int i = 0; i < 8; ++i) wfS[i * 256 + tid] = wb[i];

    bf16x8 af2[4];
    {
        int rl = w * 16 + cl;
        int sw = (cl & 7) << 3;
#pragma unroll
        for (int ks = 0; ks < 4; ++ks)
            af2[ks] = *(const bf16x8*)(mid + ((rl * DIM + kq * 8 + ks * 32) ^ sw));
    }
    __syncthreads();

    f32x4 acc2[8];
#pragma unroll
    for (int n = 0; n < 8; ++n) acc2[n] = f32x4{0.f, 0.f, 0.f, 0.f};
#pragma unroll
    for (int n = 0; n < 8; ++n)
#pragma unroll
        for (int ks = 0; ks < 4; ++ks)
            acc2[n] = __builtin_amdgcn_mfma_f32_16x16x32_bf16(af2[ks], wfS[(n * 4 + ks) * 64 + lane],
                                                              acc2[n], 0, 0, 0);

    int prow = blockIdx.x * 4 + w;
#pragma unroll
    for (int n = 0; n < 8; ++n) {
        int col = n * 16 + cl;
        float b = bias_b[col];
        float s = 0.f, q = 0.f;
#pragma unroll
        for (int r = 0; r < 4; ++r) {
            int rl = w * 16 + kq * 4 + r;
            float v = acc2[n][r] + b;
            if (rblk + rl < M) { s += v; q += v * v; }
            mid[(rl * DIM + col) ^ ((rl & 7) << 3)] = f2bf(v);
        }
        s += __shfl_xor(s, 16, 64);
        s += __shfl_xor(s, 32, 64);
        q += __shfl_xor(q, 16, 64);
        q += __shfl_xor(q, 32, 64);
        if (kq == 0) {
            psum[(size_t)prow * DIM + col] = s;
            psq[(size_t)prow * DIM + col] = q;
        }
    }

    {
        int r4 = lane >> 4, c = lane & 15;
#pragma unroll
        for (int rb = 0; rb < 4; ++rb) {
            int rl = w * 16 + rb * 4 + r4;
            int grow = rblk + rl;
            bf16x8 v = *(const bf16x8*)(mid + ((rl * DIM + c * 8) ^ ((rl & 7) << 3)));
            if (grow < M) *(bf16x8*)(out + (size_t)grow * DIM + c * 8) = v;
        }
    }
}

// ---- stats reduction stage 1 ----
__global__ __launch_bounds__(256) void reduce_stats(const float* __restrict__ psum,
                                                    const float* __restrict__ psq,
                                                    float* __restrict__ ps2) {
    int b = blockIdx.x, t = threadIdx.x;
    int c = t & 127;
    const float* src = (t < 128) ? psum : psq;
    int r0 = b * RED_ROWS;
    int r1 = min(NPART, r0 + RED_ROWS);
    float acc = 0.f;
    for (int r = r0; r < r1; ++r) acc += src[(size_t)r * DIM + c];
    ps2[(size_t)b * 256 + t] = acc;
}

// ---- BN finalize ----
__global__ __launch_bounds__(256) void bn_finalize(const float* __restrict__ ps2,
                                                   const float* __restrict__ g,
                                                   const float* __restrict__ be,
                                                   float* __restrict__ scale,
                                                   float* __restrict__ shift) {
    __shared__ float sums[128], sqs[128];
    int t = threadIdx.x;
    int c = t & 127;
    float acc = 0.f;
#pragma unroll 4
    for (int r = 0; r < RED_NB; ++r) acc += ps2[(size_t)r * 256 + t];
    if (t < 128) sums[c] = acc; else sqs[c] = acc;
    __syncthreads();
    if (t < 128) {
        const float invN = 1.0f / (float)N_NODES;
        float mu = sums[c] * invN;
        float var = sqs[c] * invN - mu * mu;
        float rs = rsqrtf(var + BN_EPS) * g[c];
        scale[c] = rs;
        shift[c] = be[c] - mu * rs;
    }
}

// ---- BN apply + ReLU + segmented pool + classifier (one block per graph) ----
__global__ __launch_bounds__(256) void bn_pool_final(const unsigned short* __restrict__ h,
                                                     const float* __restrict__ scale,
                                                     const float* __restrict__ shift,
                                                     const int* __restrict__ gs,
                                                     const float* __restrict__ Wo,
                                                     const float* __restrict__ bo,
                                                     float* __restrict__ out) {
    int g = blockIdx.x;
    int t = threadIdx.x;
    int c4 = t & 31;
    int rs = t >> 5;
    int r0 = gs[g], r1 = gs[g + 1];
    f32x4 sc = ((const f32x4*)scale)[c4];
    f32x4 sh = ((const f32x4*)shift)[c4];
    f32x4 acc = f32x4{0.f, 0.f, 0.f, 0.f};
    for (int r = r0 + rs; r < r1; r += 8) {
        u32x2 u = *(const u32x2*)(h + (size_t)r * DIM + c4 * 4);
        float f0 = bf_lo(u[0]), f1 = bf_hi(u[0]), f2 = bf_lo(u[1]), f3 = bf_hi(u[1]);
        acc[0] += fmaxf(f0 * sc[0] + sh[0], 0.f);
        acc[1] += fmaxf(f1 * sc[1] + sh[1], 0.f);
        acc[2] += fmaxf(f2 * sc[2] + sh[2], 0.f);
        acc[3] += fmaxf(f3 * sc[3] + sh[3], 0.f);
    }
    __shared__ f32x4 red[256];
    __shared__ float pf[DIM];
    red[t] = acc;
    __syncthreads();
#pragma unroll
    for (int off = 128; off >= 32; off >>= 1) {
        if (t < off) red[t] += red[t + off];
        __syncthreads();
    }
    if (t < 32) {
        f32x4 r = red[t];
        pf[t * 4 + 0] = r[0]; pf[t * 4 + 1] = r[1];
        pf[t * 4 + 2] = r[2]; pf[t * 4 + 3] = r[3];
    }
    __syncthreads();
    if (t < N_CLASSES) {
        float s = bo[t];
#pragma unroll 8
        for (int k = 0; k < DIM; ++k) s += pf[k] * Wo[k * N_CLASSES + t];
        out[g * N_CLASSES + t] = s;
    }
}

extern "C" void kernel_launch(void* const* d_in, const int* in_sizes, int n_in,
                              void* d_out, int out_size, void* d_ws, size_t ws_size,
                              hipStream_t stream) {
    const float* x   = (const float*)d_in[0];
    const int* ei    = (const int*)d_in[1];   // harness: integer -> int32
    const int* batch = (const int*)d_in[2];
    const float* W1a = (const float*)d_in[3];
    const float* b1a = (const float*)d_in[4];
    const float* W1b = (const float*)d_in[5];
    const float* b1b = (const float*)d_in[6];
    const float* g1  = (const float*)d_in[7];
    const float* be1 = (const float*)d_in[8];
    const float* W2a = (const float*)d_in[9];
    const float* b2a = (const float*)d_in[10];
    const float* W2b = (const float*)d_in[11];
    const float* b2b = (const float*)d_in[12];
    const float* g2  = (const float*)d_in[13];
    const float* be2 = (const float*)d_in[14];
    const float* Wo  = (const float*)d_in[15];
    const float* bo  = (const float*)d_in[16];

    char* ws = (char*)d_ws;
    const size_t NBH = (size_t)N_NODES * DIM * 2;   // 12.8 MB bf16 features
    unsigned short* xb   = (unsigned short*)ws;
    unsigned short* aggb = (unsigned short*)(ws + NBH);
    unsigned short* hb   = (unsigned short*)(ws + 2 * NBH);
    unsigned short* wfrag = (unsigned short*)(ws + 3 * NBH);   // 128 KB
    float* psum = (float*)(ws + 3 * NBH + 4 * 16384 * 2);      // NPART*128
    float* psq  = psum + (size_t)NPART * DIM;
    float* ps2  = psq + (size_t)NPART * DIM;       // RED_NB*256
    float* scale1  = ps2 + RED_NB * 256;
    float* shift1  = scale1 + 128;
    float* scale2  = scale1 + 256;
    float* shift2  = scale1 + 384;
    int* gs        = (int*)(shift2 + 128);         // N_GRAPHS+1
    int* gbcnt     = gs + N_GRAPHS + 1;            // NBUCK
    int* boff      = gbcnt + NBUCK;                // NBUCK+1
    int* gcur      = boff + NBUCK + 1;             // NBUCK
    int* row_start = gcur + NBUCK;                 // N_NODES+1
    unsigned* gbuf = (unsigned*)(row_start + N_NODES + 1);     // N_EDGES u32
    unsigned short* csr16 = (unsigned short*)(gbuf + N_EDGES); // N_EDGES ushort

    hipMemsetAsync(gbcnt, 0, NBUCK * 4, stream);

    prep_all<<<CVT_NB + PREPW_NB + FILL_NB + 1, 256, 0, stream>>>(
        (const f32x2*)x, (unsigned*)xb, W1a, W1b, W2a, W2b, wfrag, batch, gs, ei, gbcnt);

    bucket_scan<<<1, 256, 0, stream>>>(gbcnt, boff, gcur);
    bucket_fill<<<FILL_NB, 256, 0, stream>>>(ei, gcur, gbuf);
    csr_build<<<NBUCK, 256, 0, stream>>>(gbuf, boff, csr16, row_start);

    const int ablk = (N_NODES + 3) / 4;

    // layer 1
    aggregate_bf<false><<<ablk, 256, 0, stream>>>((const u32x2*)xb, (u32x2*)aggb,
                                                  row_start, csr16, nullptr, nullptr);
    fused_layer<<<FBLK, 256, 0, stream>>>(
        aggb, (const bf16x8*)(wfrag + 0 * 16384), (const bf16x8*)(wfrag + 1 * 16384),
        b1a, b1b, hb, psum, psq, N_NODES);
    reduce_stats<<<RED_NB, 256, 0, stream>>>(psum, psq, ps2);
    bn_finalize<<<1, 256, 0, stream>>>(ps2, g1, be1, scale1, shift1);

    // layer 2 (BN1+ReLU fused into aggregate)
    aggregate_bf<true><<<ablk, 256, 0, stream>>>((const u32x2*)hb, (u32x2*)aggb,
                                                 row_start, csr16, scale1, shift1);
    fused_layer<<<FBLK, 256, 0, stream>>>(
        aggb, (const bf16x8*)(wfrag + 2 * 16384), (const bf16x8*)(wfrag + 3 * 16384),
        b2a, b2b, hb, psum, psq, N_NODES);
    reduce_stats<<<RED_NB, 256, 0, stream>>>(psum, psq, ps2);
    bn_finalize<<<1, 256, 0, stream>>>(ps2, g2, be2, scale2, shift2);

    bn_pool_final<<<N_GRAPHS, 256, 0, stream>>>(hb, scale2, shift2, gs, Wo, bo,
                                                (float*)d_out);
}

// Round 15
// 220.896 us; speedup vs baseline: 2.1600x; 1.0035x over previous
//
#include <hip/hip_runtime.h>

typedef __attribute__((ext_vector_type(8))) short bf16x8;
typedef __attribute__((ext_vector_type(4))) float f32x4;
typedef __attribute__((ext_vector_type(2))) float f32x2;
typedef __attribute__((ext_vector_type(2))) unsigned u32x2;

#define N_NODES 50000
#define N_EDGES 800000
#define DIM 128
#define N_GRAPHS 128
#define N_CLASSES 10
#define BN_EPS 1e-5f
#define FBLK ((N_NODES + 63) / 64)        // 782 row tiles
#define FGRID (FBLK / 2)                  // 391 blocks, 2 tiles each
#define NPART (FBLK * 4)                  // 3128 stat-partial rows
#define RED_NB 64
#define RED_ROWS ((NPART + RED_NB - 1) / RED_NB)   // 49

#define NBUCK 196                         // dst buckets of 256 nodes
#define FILL_NB 400
#define FILL_PER (N_EDGES / FILL_NB)      // 2000
#define BMAX 6144                         // max bucket size

#define CVT_NB (N_NODES * 64 / 256)       // 12500
#define PREPW_NB 256

static __device__ __forceinline__ unsigned short f2bf(float f) {
    unsigned u = __float_as_uint(f);
    u += 0x7FFF + ((u >> 16) & 1);   // round-to-nearest-even
    return (unsigned short)(u >> 16);
}
static __device__ __forceinline__ float bf_lo(unsigned u) { return __uint_as_float(u << 16); }
static __device__ __forceinline__ float bf_hi(unsigned u) { return __uint_as_float(u & 0xffff0000u); }
static __device__ __forceinline__ unsigned packbf(float a, float b) {
    return (unsigned)f2bf(a) | ((unsigned)f2bf(b) << 16);
}

// ---- fused prep: x->bf16 | W permute | graph starts | bucket_count ----
__global__ __launch_bounds__(256) void prep_all(const f32x2* __restrict__ x,
                                                unsigned* __restrict__ xb,
                                                const float* __restrict__ W0,
                                                const float* __restrict__ W1,
                                                const float* __restrict__ W2,
                                                const float* __restrict__ W3,
                                                unsigned short* __restrict__ wf,
                                                const int* __restrict__ batch,
                                                int* __restrict__ gs,
                                                const int* __restrict__ ei,
                                                int* __restrict__ gbcnt) {
    int b = blockIdx.x, tid = threadIdx.x;
    if (b < CVT_NB) {
        int t = b * 256 + tid;
        f32x2 v = x[t];
        xb[t] = packbf(v[0], v[1]);
    } else if (b < CVT_NB + PREPW_NB) {
        int t = (b - CVT_NB) * 256 + tid;
        int m = t >> 14, rem = t & 16383;
        int e = rem & 7, lane = (rem >> 3) & 63, fi = rem >> 9;
        int ks = fi & 3, n = fi >> 2;
        int col = n * 16 + (lane & 15);
        int k = ks * 32 + ((lane >> 4) << 3) + e;
        const float* W = (m == 0) ? W0 : (m == 1) ? W1 : (m == 2) ? W2 : W3;
        wf[t] = f2bf(W[k * DIM + col]);
    } else if (b < CVT_NB + PREPW_NB + FILL_NB) {
        __shared__ int cnt[NBUCK];
        if (tid < NBUCK) cnt[tid] = 0;
        __syncthreads();
        int e0 = (b - CVT_NB - PREPW_NB) * FILL_PER;
        for (int c = tid; c < FILL_PER; c += 256) {
            int dst = ei[N_EDGES + e0 + c];
            atomicAdd(&cnt[dst >> 8], 1);
        }
        __syncthreads();
        if (tid < NBUCK) atomicAdd(&gbcnt[tid], cnt[tid]);
    } else {
        int g = tid;
        if (g > N_GRAPHS) return;
        int lo = 0, hi = N_NODES;
        while (lo < hi) {
            int mid = (lo + hi) >> 1;
            if (batch[mid] < g) lo = mid + 1; else hi = mid;
        }
        gs[g] = lo;
    }
}

// ---- CSR build stage 2: scan 196 bucket counts; init cursors ----
__global__ __launch_bounds__(256) void bucket_scan(const int* __restrict__ gbcnt,
                                                   int* __restrict__ boff,
                                                   int* __restrict__ gcur) {
    __shared__ int buf[256];
    int t = threadIdx.x;
    int v = (t < NBUCK) ? gbcnt[t] : 0;
    buf[t] = v;
    __syncthreads();
#pragma unroll
    for (int off = 1; off < 256; off <<= 1) {
        int u = (t >= off) ? buf[t - off] : 0;
        __syncthreads();
        buf[t] += u;
        __syncthreads();
    }
    if (t < NBUCK) { int ex = buf[t] - v; boff[t] = ex; gcur[t] = ex; }
    if (t == 0) boff[NBUCK] = N_EDGES;
}

// ---- CSR build stage 3: block-local counting sort by bucket ----
__global__ __launch_bounds__(256) void bucket_fill(const int* __restrict__ ei,
                                                   int* __restrict__ gcur,
                                                   unsigned* __restrict__ gbuf) {
    __shared__ unsigned ent[FILL_PER];
    __shared__ unsigned srt[FILL_PER];
    __shared__ int cnt[256], c2[256], lofs[256], gbase[256];
    int tid = threadIdx.x;
    int e0 = blockIdx.x * FILL_PER;
    cnt[tid] = 0; c2[tid] = 0;
    __syncthreads();
    for (int i = tid; i < FILL_PER; i += 256) {
        int src = ei[e0 + i];
        int dst = ei[N_EDGES + e0 + i];
        ent[i] = (unsigned)src | ((unsigned)(dst & 255) << 16) | ((unsigned)(dst >> 8) << 24);
        atomicAdd(&cnt[dst >> 8], 1);
    }
    __syncthreads();
    int v = cnt[tid];
    lofs[tid] = v;
    __syncthreads();
#pragma unroll
    for (int off = 1; off < 256; off <<= 1) {
        int u = (tid >= off) ? lofs[tid - off] : 0;
        __syncthreads();
        lofs[tid] += u;
        __syncthreads();
    }
    int excl = lofs[tid] - v;
    lofs[tid] = excl;
    if (tid < NBUCK && v > 0) gbase[tid] = atomicAdd(&gcur[tid], v);
    __syncthreads();
    for (int i = tid; i < FILL_PER; i += 256) {
        unsigned w = ent[i];
        int b = w >> 24;
        int r = atomicAdd(&c2[b], 1);
        srt[lofs[b] + r] = w;
    }
    __syncthreads();
    for (int i = tid; i < FILL_PER; i += 256) {
        unsigned w = srt[i];
        int b = w >> 24;
        gbuf[gbase[b] + (i - lofs[b])] = w;
    }
}

// ---- CSR build stage 4: per-bucket in-LDS sort -> row_start + ushort csr ----
__global__ __launch_bounds__(256) void csr_build(const unsigned* __restrict__ gbuf,
                                                 const int* __restrict__ boff,
                                                 unsigned short* __restrict__ csr16,
                                                 int* __restrict__ row_start) {
    __shared__ unsigned ent[BMAX];
    __shared__ unsigned short csl[BMAX];
    __shared__ int cnt[256], c2[256], offs[256];
    int b = blockIdx.x, t = threadIdx.x;
    int base = boff[b], n = boff[b + 1] - base;
    for (int i = t; i < n; i += 256) ent[i] = gbuf[base + i];
    cnt[t] = 0; c2[t] = 0;
    __syncthreads();
    for (int i = t; i < n; i += 256) atomicAdd(&cnt[(ent[i] >> 16) & 255], 1);
    __syncthreads();
    int v = cnt[t];
    offs[t] = v;
    __syncthreads();
#pragma unroll
    for (int off = 1; off < 256; off <<= 1) {
        int u = (t >= off) ? offs[t - off] : 0;
        __syncthreads();
        offs[t] += u;
        __syncthreads();
    }
    int excl = offs[t] - v;
    int node = b * 256 + t;
    if (node < N_NODES) row_start[node] = base + excl;
    if (b == NBUCK - 1 && t == 0) row_start[N_NODES] = N_EDGES;
    __syncthreads();
    offs[t] = excl;
    __syncthreads();
    for (int i = t; i < n; i += 256) {
        unsigned w = ent[i];
        int d = (w >> 16) & 255;
        int r = atomicAdd(&c2[d], 1);
        csl[offs[d] + r] = (unsigned short)(w & 0xffffu);
    }
    __syncthreads();
    for (int i = t; i < n; i += 256) csr16[base + i] = csl[i];
}

// ---- gather-sum aggregation: lane-parallel index preload, UNIFORM loop (safe shfl) ----
template <bool BN>
__global__ __launch_bounds__(256) void aggregate_bf(const u32x2* __restrict__ F2,
                                                    u32x2* __restrict__ out,
                                                    const int* __restrict__ row_start,
                                                    const unsigned short* __restrict__ csr16,
                                                    const float* __restrict__ scale,
                                                    const float* __restrict__ shift) {
    int wave = threadIdx.x >> 6, lane = threadIdx.x & 63;
    int v = blockIdx.x * 4 + wave;
    if (v >= N_NODES) return;
    int half = lane >> 5;
    int c4 = lane & 31;
    f32x4 sc, sh;
    if (BN) {
        sc = ((const f32x4*)scale)[c4];
        sh = ((const f32x4*)shift)[c4];
    }
    int e0 = row_start[v];
    int n = row_start[v + 1] - e0;
    int myidx = (lane < n) ? (int)csr16[e0 + lane] : 0;
    int n64 = (n < 64) ? n : 64;   // wave-uniform

    f32x4 a0 = f32x4{0.f, 0.f, 0.f, 0.f};
    f32x4 a1 = f32x4{0.f, 0.f, 0.f, 0.f};
    if (half == 0) {   // self term
        u32x2 u = F2[(size_t)v * 32 + c4];
        a0[0] = bf_lo(u[0]); a0[1] = bf_hi(u[0]);
        a0[2] = bf_lo(u[1]); a0[3] = bf_hi(u[1]);
        if (BN) {
#pragma unroll
            for (int k = 0; k < 4; ++k) a0[k] = fmaxf(a0[k] * sc[k] + sh[k], 0.f);
        }
    }

    for (int base = 0; base < n64; base += 8) {   // uniform trip count, safe shfl
        int j0 = base + half, j1 = j0 + 2, j2 = j0 + 4, j3 = j0 + 6;
        int s0 = __shfl(myidx, j0 & 63, 64);
        int s1 = __shfl(myidx, j1 & 63, 64);
        int s2 = __shfl(myidx, j2 & 63, 64);
        int s3 = __shfl(myidx, j3 & 63, 64);
        u32x2 ua = F2[(size_t)s0 * 32 + c4];
        u32x2 ub = F2[(size_t)s1 * 32 + c4];
        u32x2 uc = F2[(size_t)s2 * 32 + c4];
        u32x2 ud = F2[(size_t)s3 * 32 + c4];
        float p0 = bf_lo(ua[0]), p1 = bf_hi(ua[0]), p2 = bf_lo(ua[1]), p3 = bf_hi(ua[1]);
        float q0 = bf_lo(ub[0]), q1 = bf_hi(ub[0]), q2 = bf_lo(ub[1]), q3 = bf_hi(ub[1]);
        float r0 = bf_lo(uc[0]), r1 = bf_hi(uc[0]), r2 = bf_lo(uc[1]), r3 = bf_hi(uc[1]);
        float t0 = bf_lo(ud[0]), t1 = bf_hi(ud[0]), t2 = bf_lo(ud[1]), t3 = bf_hi(ud[1]);
        if (BN) {
            p0 = fmaxf(p0 * sc[0] + sh[0], 0.f); p1 = fmaxf(p1 * sc[1] + sh[1], 0.f);
            p2 = fmaxf(p2 * sc[2] + sh[2], 0.f); p3 = fmaxf(p3 * sc[3] + sh[3], 0.f);
            q0 = fmaxf(q0 * sc[0] + sh[0], 0.f); q1 = fmaxf(q1 * sc[1] + sh[1], 0.f);
            q2 = fmaxf(q2 * sc[2] + sh[2], 0.f); q3 = fmaxf(q3 * sc[3] + sh[3], 0.f);
            r0 = fmaxf(r0 * sc[0] + sh[0], 0.f); r1 = fmaxf(r1 * sc[1] + sh[1], 0.f);
            r2 = fmaxf(r2 * sc[2] + sh[2], 0.f); r3 = fmaxf(r3 * sc[3] + sh[3], 0.f);
            t0 = fmaxf(t0 * sc[0] + sh[0], 0.f); t1 = fmaxf(t1 * sc[1] + sh[1], 0.f);
            t2 = fmaxf(t2 * sc[2] + sh[2], 0.f); t3 = fmaxf(t3 * sc[3] + sh[3], 0.f);
        }
        if (j0 < n64) { a0[0] += p0; a0[1] += p1; a0[2] += p2; a0[3] += p3; }
        if (j1 < n64) { a0[0] += q0; a0[1] += q1; a0[2] += q2; a0[3] += q3; }
        if (j2 < n64) { a1[0] += r0; a1[1] += r1; a1[2] += r2; a1[3] += r3; }
        if (j3 < n64) { a1[0] += t0; a1[1] += t1; a1[2] += t2; a1[3] += t3; }
    }
    for (int j = 64 + half; j < n; j += 2) {   // rare: degree > 64 (no shfl)
        int s = csr16[e0 + j];
        u32x2 ua = F2[(size_t)s * 32 + c4];
        float p0 = bf_lo(ua[0]), p1 = bf_hi(ua[0]), p2 = bf_lo(ua[1]), p3 = bf_hi(ua[1]);
        if (BN) {
            p0 = fmaxf(p0 * sc[0] + sh[0], 0.f); p1 = fmaxf(p1 * sc[1] + sh[1], 0.f);
            p2 = fmaxf(p2 * sc[2] + sh[2], 0.f); p3 = fmaxf(p3 * sc[3] + sh[3], 0.f);
        }
        a0[0] += p0; a0[1] += p1; a0[2] += p2; a0[3] += p3;
    }
#pragma unroll
    for (int k = 0; k < 4; ++k) a0[k] += a1[k];
#pragma unroll
    for (int k = 0; k < 4; ++k) a0[k] += __shfl_xor(a0[k], 32, 64);
    if (half == 0) {
        u32x2 w;
        w[0] = packbf(a0[0], a0[1]);
        w[1] = packbf(a0[2], a0[3]);
        out[(size_t)v * 32 + c4] = w;
    }
}

// ---- fused GIN layer: 2 row-tiles per block; Wa+Wb held in regs, staged per phase ----
// grid FGRID=391 (all co-resident at 3 blk/CU); LDS 48KB; W global-loaded ONCE per block
__global__ __launch_bounds__(256, 3) void fused_layer(
        const unsigned short* __restrict__ A,
        const bf16x8* __restrict__ wfA_g,
        const bf16x8* __restrict__ wfB_g,
        const float* __restrict__ bias_a,
        const float* __restrict__ bias_b,
        unsigned short* __restrict__ out,
        float* __restrict__ psum,
        float* __restrict__ psq, int M) {
    __shared__ bf16x8 wfS[2048];                // 32 KB, Wa then Wb per tile
    __shared__ unsigned short mid[8192];        // 64 x 128

    int tid = threadIdx.x;
    int w = tid >> 6, lane = tid & 63;
    int cl = lane & 15, kq = lane >> 4;

    bf16x8 wa[8], wb[8];
#pragma unroll
    for (int i = 0; i < 8; ++i) wa[i] = wfA_g[i * 256 + tid];
#pragma unroll
    for (int i = 0; i < 8; ++i) wb[i] = wfB_g[i * 256 + tid];

    for (int t = 0; t < 2; ++t) {
        int tile = blockIdx.x + t * FGRID;
        int rblk = tile * 64;

        // stage Wa (loop-end barrier guarantees prior tile's wfS/mid uses are done)
#pragma unroll
        for (int i = 0; i < 8; ++i) wfS[i * 256 + tid] = wa[i];

        int arow = rblk + w * 16 + cl;
        if (arow >= M) arow = M - 1;
        bf16x8 af[4];
        const unsigned short* Ap = A + (size_t)arow * DIM + kq * 8;
#pragma unroll
        for (int ks = 0; ks < 4; ++ks) af[ks] = *(const bf16x8*)(Ap + ks * 32);

        __syncthreads();   // Wa staged

        f32x4 acc[8];
#pragma unroll
        for (int n = 0; n < 8; ++n) acc[n] = f32x4{0.f, 0.f, 0.f, 0.f};
#pragma unroll
        for (int n = 0; n < 8; ++n)
#pragma unroll
            for (int ks = 0; ks < 4; ++ks)
                acc[n] = __builtin_amdgcn_mfma_f32_16x16x32_bf16(
                    af[ks], wfS[(n * 4 + ks) * 64 + lane], acc[n], 0, 0, 0);

#pragma unroll
        for (int n = 0; n < 8; ++n) {
            int col = n * 16 + cl;
            float b = bias_a[col];
#pragma unroll
            for (int r = 0; r < 4; ++r) {
                int rl = w * 16 + kq * 4 + r;
                float v = fmaxf(acc[n][r] + b, 0.f);
                mid[(rl * DIM + col) ^ ((rl & 7) << 3)] = f2bf(v);
            }
        }
        __syncthreads();   // GEMM1 wfS reads done; mid fully written

#pragma unroll
        for (int i = 0; i < 8; ++i) wfS[i * 256 + tid] = wb[i];

        bf16x8 af2[4];
        {
            int rl = w * 16 + cl;
            int sw = (cl & 7) << 3;
#pragma unroll
            for (int ks = 0; ks < 4; ++ks)
                af2[ks] = *(const bf16x8*)(mid + ((rl * DIM + kq * 8 + ks * 32) ^ sw));
        }
        __syncthreads();   // Wb staged; all af2 reads of mid done

        f32x4 acc2[8];
#pragma unroll
        for (int n = 0; n < 8; ++n) acc2[n] = f32x4{0.f, 0.f, 0.f, 0.f};
#pragma unroll
        for (int n = 0; n < 8; ++n)
#pragma unroll
            for (int ks = 0; ks < 4; ++ks)
                acc2[n] = __builtin_amdgcn_mfma_f32_16x16x32_bf16(
                    af2[ks], wfS[(n * 4 + ks) * 64 + lane], acc2[n], 0, 0, 0);

        int prow = tile * 4 + w;
#pragma unroll
        for (int n = 0; n < 8; ++n) {
            int col = n * 16 + cl;
            float b = bias_b[col];
            float s = 0.f, q = 0.f;
#pragma unroll
            for (int r = 0; r < 4; ++r) {
                int rl = w * 16 + kq * 4 + r;
                float v = acc2[n][r] + b;
                if (rblk + rl < M) { s += v; q += v * v; }
                mid[(rl * DIM + col) ^ ((rl & 7) << 3)] = f2bf(v);
            }
            s += __shfl_xor(s, 16, 64);
            s += __shfl_xor(s, 32, 64);
            q += __shfl_xor(q, 16, 64);
            q += __shfl_xor(q, 32, 64);
            if (kq == 0) {
                psum[(size_t)prow * DIM + col] = s;
                psq[(size_t)prow * DIM + col] = q;
            }
        }

        {   // bounce-store (wave-private mid slice)
            int r4 = lane >> 4, c = lane & 15;
#pragma unroll
            for (int rb = 0; rb < 4; ++rb) {
                int rl = w * 16 + rb * 4 + r4;
                int grow = rblk + rl;
                bf16x8 v = *(const bf16x8*)(mid + ((rl * DIM + c * 8) ^ ((rl & 7) << 3)));
                if (grow < M) *(bf16x8*)(out + (size_t)grow * DIM + c * 8) = v;
            }
        }
        __syncthreads();   // end-of-tile: wfS(Wb) reads + mid uses complete
    }
}

// ---- stats reduction stage 1 ----
__global__ __launch_bounds__(256) void reduce_stats(const float* __restrict__ psum,
                                                    const float* __restrict__ psq,
                                                    float* __restrict__ ps2) {
    int b = blockIdx.x, t = threadIdx.x;
    int c = t & 127;
    const float* src = (t < 128) ? psum : psq;
    int r0 = b * RED_ROWS;
    int r1 = min(NPART, r0 + RED_ROWS);
    float acc = 0.f;
    for (int r = r0; r < r1; ++r) acc += src[(size_t)r * DIM + c];
    ps2[(size_t)b * 256 + t] = acc;
}

// ---- BN finalize ----
__global__ __launch_bounds__(256) void bn_finalize(const float* __restrict__ ps2,
                                                   const float* __restrict__ g,
                                                   const float* __restrict__ be,
                                                   float* __restrict__ scale,
                                                   float* __restrict__ shift) {
    __shared__ float sums[128], sqs[128];
    int t = threadIdx.x;
    int c = t & 127;
    float acc = 0.f;
#pragma unroll 4
    for (int r = 0; r < RED_NB; ++r) acc += ps2[(size_t)r * 256 + t];
    if (t < 128) sums[c] = acc; else sqs[c] = acc;
    __syncthreads();
    if (t < 128) {
        const float invN = 1.0f / (float)N_NODES;
        float mu = sums[c] * invN;
        float var = sqs[c] * invN - mu * mu;
        float rs = rsqrtf(var + BN_EPS) * g[c];
        scale[c] = rs;
        shift[c] = be[c] - mu * rs;
    }
}

// ---- BN apply + ReLU + segmented pool + classifier (one block per graph) ----
__global__ __launch_bounds__(256) void bn_pool_final(const unsigned short* __restrict__ h,
                                                     const float* __restrict__ scale,
                                                     const float* __restrict__ shift,
                                                     const int* __restrict__ gs,
                                                     const float* __restrict__ Wo,
                                                     const float* __restrict__ bo,
                                                     float* __restrict__ out) {
    int g = blockIdx.x;
    int t = threadIdx.x;
    int c4 = t & 31;
    int rs = t >> 5;
    int r0 = gs[g], r1 = gs[g + 1];
    f32x4 sc = ((const f32x4*)scale)[c4];
    f32x4 sh = ((const f32x4*)shift)[c4];
    f32x4 acc = f32x4{0.f, 0.f, 0.f, 0.f};
    for (int r = r0 + rs; r < r1; r += 8) {
        u32x2 u = *(const u32x2*)(h + (size_t)r * DIM + c4 * 4);
        float f0 = bf_lo(u[0]), f1 = bf_hi(u[0]), f2 = bf_lo(u[1]), f3 = bf_hi(u[1]);
        acc[0] += fmaxf(f0 * sc[0] + sh[0], 0.f);
        acc[1] += fmaxf(f1 * sc[1] + sh[1], 0.f);
        acc[2] += fmaxf(f2 * sc[2] + sh[2], 0.f);
        acc[3] += fmaxf(f3 * sc[3] + sh[3], 0.f);
    }
    __shared__ f32x4 red[256];
    __shared__ float pf[DIM];
    red[t] = acc;
    __syncthreads();
#pragma unroll
    for (int off = 128; off >= 32; off >>= 1) {
        if (t < off) red[t] += red[t + off];
        __syncthreads();
    }
    if (t < 32) {
        f32x4 r = red[t];
        pf[t * 4 + 0] = r[0]; pf[t * 4 + 1] = r[1];
        pf[t * 4 + 2] = r[2]; pf[t * 4 + 3] = r[3];
    }
    __syncthreads();
    if (t < N_CLASSES) {
        float s = bo[t];
#pragma unroll 8
        for (int k = 0; k < DIM; ++k) s += pf[k] * Wo[k * N_CLASSES + t];
        out[g * N_CLASSES + t] = s;
    }
}

extern "C" void kernel_launch(void* const* d_in, const int* in_sizes, int n_in,
                              void* d_out, int out_size, void* d_ws, size_t ws_size,
                              hipStream_t stream) {
    const float* x   = (const float*)d_in[0];
    const int* ei    = (const int*)d_in[1];   // harness: integer -> int32
    const int* batch = (const int*)d_in[2];
    const float* W1a = (const float*)d_in[3];
    const float* b1a = (const float*)d_in[4];
    const float* W1b = (const float*)d_in[5];
    const float* b1b = (const float*)d_in[6];
    const float* g1  = (const float*)d_in[7];
    const float* be1 = (const float*)d_in[8];
    const float* W2a = (const float*)d_in[9];
    const float* b2a = (const float*)d_in[10];
    const float* W2b = (const float*)d_in[11];
    const float* b2b = (const float*)d_in[12];
    const float* g2  = (const float*)d_in[13];
    const float* be2 = (const float*)d_in[14];
    const float* Wo  = (const float*)d_in[15];
    const float* bo  = (const float*)d_in[16];

    char* ws = (char*)d_ws;
    const size_t NBH = (size_t)N_NODES * DIM * 2;   // 12.8 MB bf16 features
    unsigned short* xb   = (unsigned short*)ws;
    unsigned short* aggb = (unsigned short*)(ws + NBH);
    unsigned short* hb   = (unsigned short*)(ws + 2 * NBH);
    unsigned short* wfrag = (unsigned short*)(ws + 3 * NBH);   // 128 KB
    float* psum = (float*)(ws + 3 * NBH + 4 * 16384 * 2);      // NPART*128
    float* psq  = psum + (size_t)NPART * DIM;
    float* ps2  = psq + (size_t)NPART * DIM;       // RED_NB*256
    float* scale1  = ps2 + RED_NB * 256;
    float* shift1  = scale1 + 128;
    float* scale2  = scale1 + 256;
    float* shift2  = scale1 + 384;
    int* gs        = (int*)(shift2 + 128);         // N_GRAPHS+1
    int* gbcnt     = gs + N_GRAPHS + 1;            // NBUCK
    int* boff      = gbcnt + NBUCK;                // NBUCK+1
    int* gcur      = boff + NBUCK + 1;             // NBUCK
    int* row_start = gcur + NBUCK;                 // N_NODES+1
    unsigned* gbuf = (unsigned*)(row_start + N_NODES + 1);     // N_EDGES u32
    unsigned short* csr16 = (unsigned short*)(gbuf + N_EDGES); // N_EDGES ushort

    hipMemsetAsync(gbcnt, 0, NBUCK * 4, stream);

    prep_all<<<CVT_NB + PREPW_NB + FILL_NB + 1, 256, 0, stream>>>(
        (const f32x2*)x, (unsigned*)xb, W1a, W1b, W2a, W2b, wfrag, batch, gs, ei, gbcnt);

    bucket_scan<<<1, 256, 0, stream>>>(gbcnt, boff, gcur);
    bucket_fill<<<FILL_NB, 256, 0, stream>>>(ei, gcur, gbuf);
    csr_build<<<NBUCK, 256, 0, stream>>>(gbuf, boff, csr16, row_start);

    const int ablk = (N_NODES + 3) / 4;

    // layer 1
    aggregate_bf<false><<<ablk, 256, 0, stream>>>((const u32x2*)xb, (u32x2*)aggb,
                                                  row_start, csr16, nullptr, nullptr);
    fused_layer<<<FGRID, 256, 0, stream>>>(
        aggb, (const bf16x8*)(wfrag + 0 * 16384), (const bf16x8*)(wfrag + 1 * 16384),
        b1a, b1b, hb, psum, psq, N_NODES);
    reduce_stats<<<RED_NB, 256, 0, stream>>>(psum, psq, ps2);
    bn_finalize<<<1, 256, 0, stream>>>(ps2, g1, be1, scale1, shift1);

    // layer 2 (BN1+ReLU fused into aggregate)
    aggregate_bf<true><<<ablk, 256, 0, stream>>>((const u32x2*)hb, (u32x2*)aggb,
                                                 row_start, csr16, scale1, shift1);
    fused_layer<<<FGRID, 256, 0, stream>>>(
        aggb, (const bf16x8*)(wfrag + 2 * 16384), (const bf16x8*)(wfrag + 3 * 16384),
        b2a, b2b, hb, psum, psq, N_NODES);
    reduce_stats<<<RED_NB, 256, 0, stream>>>(psum, psq, ps2);
    bn_finalize<<<1, 256, 0, stream>>>(ps2, g2, be2, scale2, shift2);

    bn_pool_final<<<N_GRAPHS, 256, 0, stream>>>(hb, scale2, shift2, gs, Wo, bo,
                                                (float*)d_out);
}